// Round 1
// baseline (4512.520 us; speedup 1.0000x reference)
//
#include <hip/hip_runtime.h>
#include <hip/hip_bf16.h>
#include <math.h>

#define B_ 2
#define S_ 4096
#define E_ 512
#define H_ 8
#define D_ 64
#define W_ 512
#define NW_ 8

typedef float f32x4 __attribute__((ext_vector_type(4)));
typedef short s16x4 __attribute__((ext_vector_type(4)));
typedef short s16x8 __attribute__((ext_vector_type(8)));

__device__ inline short f2bf(float f) {
    unsigned u = __builtin_bit_cast(unsigned, f);
    unsigned r = (u + 0x7FFFu + ((u >> 16) & 1u)) >> 16;
    return (short)r;
}

// ---------------------------------------------------------------------------
// Projection GEMM: C[M=8192][N=512] = A[M][K=512] * W[K][N] * scale
// bf16 MFMA 16x16x32, 128x128 block tile, 256 threads = 4 waves (2x2 of 64x64)
// ---------------------------------------------------------------------------
#define LDA 40  // padded LDS row stride in bf16 elements (80B: 2-way max conflict)

__global__ __launch_bounds__(256, 2)
void proj_kernel(const float* __restrict__ A, const float* __restrict__ Wg,
                 float* __restrict__ C, float scale)
{
    __shared__ short As[128][LDA];
    __shared__ short Bs[128][LDA];  // Bs[n][k] = W[k][n]

    const int tid  = threadIdx.x;
    const int m0   = blockIdx.x * 128;
    const int n0   = blockIdx.y * 128;
    const int wave = tid >> 6;
    const int lane = tid & 63;
    const int wm   = (wave & 1) * 64;
    const int wn   = (wave >> 1) * 64;
    const int lr   = lane & 15;
    const int quad = lane >> 4;

    f32x4 acc[4][4] = {};

    const int sar = tid >> 3;        // 0..31
    const int sac = (tid & 7) * 4;   // 0,4,...,28

    for (int k0 = 0; k0 < 512; k0 += 32) {
        // stage A tile (128 x 32), fp32 -> bf16
        #pragma unroll
        for (int it = 0; it < 4; ++it) {
            int row = sar + 32 * it;
            f32x4 v = *(const f32x4*)(A + (size_t)(m0 + row) * 512 + k0 + sac);
            s16x4 bv; bv[0]=f2bf(v[0]); bv[1]=f2bf(v[1]); bv[2]=f2bf(v[2]); bv[3]=f2bf(v[3]);
            *(s16x4*)&As[row][sac] = bv;
        }
        // stage B tile transposed: Bs[n][k] = W[k][n]
        {
            int kk = (tid & 7) * 4;      // 0..28
            #pragma unroll
            for (int it = 0; it < 4; ++it) {
                int nn = (tid >> 3) + 32 * it;  // 0..127
                s16x4 bv;
                #pragma unroll
                for (int jj = 0; jj < 4; ++jj)
                    bv[jj] = f2bf(Wg[(size_t)(k0 + kk + jj) * 512 + n0 + nn]);
                *(s16x4*)&Bs[nn][kk] = bv;
            }
        }
        __syncthreads();

        s16x8 af[4], bf[4];
        #pragma unroll
        for (int t = 0; t < 4; ++t) {
            af[t] = *(const s16x8*)&As[wm + t * 16 + lr][quad * 8];
            bf[t] = *(const s16x8*)&Bs[wn + t * 16 + lr][quad * 8];
        }
        #pragma unroll
        for (int tm = 0; tm < 4; ++tm)
            #pragma unroll
            for (int tn = 0; tn < 4; ++tn)
                acc[tm][tn] = __builtin_amdgcn_mfma_f32_16x16x32_bf16(
                    af[tm], bf[tn], acc[tm][tn], 0, 0, 0);
        __syncthreads();
    }

    // epilogue: C/D layout col=lane&15, row=quad*4+reg
    #pragma unroll
    for (int tm = 0; tm < 4; ++tm)
        #pragma unroll
        for (int tn = 0; tn < 4; ++tn) {
            int col = n0 + wn + tn * 16 + lr;
            #pragma unroll
            for (int gg = 0; gg < 4; ++gg) {
                int row = m0 + wm + tm * 16 + quad * 4 + gg;
                C[(size_t)row * 512 + col] = acc[tm][tn][gg] * scale;
            }
        }
}

// ---------------------------------------------------------------------------
// Attention: block = (b, window n, head h, 32-row q tile); online softmax,
// K/V chunks of 128 staged in LDS. All fp32 this round.
// ---------------------------------------------------------------------------
#define QT 32

__device__ inline void stage_kv(const float* __restrict__ cur,
                                const float* __restrict__ prev,
                                int b, int n, int h, int jb, int tid,
                                float kv[128][68])
{
    int cc = tid >> 1;
    int dh = (tid & 1) * 32;
    int j  = jb + cc;
    if (j < 2 * W_) {
        int p = n * W_ + j - W_;
        const float* src = (p >= 0)
            ? (cur  + (((size_t)b * S_ + p) * H_ + h) * D_ + dh)
            : (prev + (((size_t)b * W_ + j) * H_ + h) * D_ + dh);
        #pragma unroll
        for (int t4 = 0; t4 < 8; ++t4)
            *(f32x4*)&kv[cc][dh + 4 * t4] = *(const f32x4*)(src + 4 * t4);
    } else {
        #pragma unroll
        for (int t4 = 0; t4 < 8; ++t4)
            *(f32x4*)&kv[cc][dh + 4 * t4] = (f32x4){0.f, 0.f, 0.f, 0.f};
    }
}

__global__ __launch_bounds__(256, 2)
void attn_kernel(const float* __restrict__ q, const float* __restrict__ k,
                 const float* __restrict__ v, const float* __restrict__ prev_k,
                 const float* __restrict__ prev_v, const float* __restrict__ rel_bias,
                 float* __restrict__ out)
{
    __shared__ float q_s[QT][68];
    __shared__ float kv_s[128][68];
    __shared__ float s_s[QT][132];
    __shared__ float bias_s[512];
    __shared__ float m_s[QT], l_s[QT], a_s[QT];
    __shared__ float red_s[QT][8];

    const int bid = blockIdx.x;
    const int qt = bid & 15;
    const int h  = (bid >> 4) & 7;
    const int n  = (bid >> 7) & 7;
    const int b  = bid >> 10;
    const int tid = threadIdx.x;
    const int r  = tid >> 3;       // 0..31 local q row
    const int g  = tid & 7;        // column/dim group
    const int i  = qt * QT + r;    // q row in window [0,512)

    // per-head bias table over distance nd = i + 512 - j in [0,512)
    for (int nd = tid; nd < 512; nd += 256) {
        int bucket;
        if (nd < 16) bucket = nd;
        else {
            int vb = 16 + (int)(log((double)nd * (1.0 / 16.0)) * (16.0 / log(8.0)));
            bucket = vb < 31 ? vb : 31;
        }
        bias_s[nd] = rel_bias[h * 32 + bucket];
    }

    // load q tile (already scaled by 1/8 in projection)
    {
        int d0 = g * 8;
        const float* src = q + (((size_t)b * S_ + n * W_ + i) * H_ + h) * D_ + d0;
        *(f32x4*)&q_s[r][d0]     = *(const f32x4*)(src);
        *(f32x4*)&q_s[r][d0 + 4] = *(const f32x4*)(src + 4);
    }
    if (tid < QT) { m_s[tid] = -1e30f; l_s[tid] = 0.f; }

    float o[8];
    #pragma unroll
    for (int jj = 0; jj < 8; ++jj) o[jj] = 0.f;
    const int d0 = g * 8;

    __syncthreads();

    for (int c5 = 0; c5 < 5; ++c5) {
        const int jb = qt * QT + c5 * 128;

        // phase 1: stage K chunk
        stage_kv(k, prev_k, b, n, h, jb, tid, kv_s);
        __syncthreads();

        // phase 2: scores for 16 columns (cc = g + 8*idx), partial row max
        float accv[16];
        #pragma unroll
        for (int idx = 0; idx < 16; ++idx) accv[idx] = 0.f;
        for (int d = 0; d < 64; d += 4) {
            f32x4 qv = *(const f32x4*)&q_s[r][d];
            #pragma unroll
            for (int idx = 0; idx < 16; ++idx) {
                f32x4 kf = *(const f32x4*)&kv_s[g + 8 * idx][d];
                accv[idx] += qv[0]*kf[0] + qv[1]*kf[1] + qv[2]*kf[2] + qv[3]*kf[3];
            }
        }
        float pm = -1e30f;
        #pragma unroll
        for (int idx = 0; idx < 16; ++idx) {
            int cc = g + 8 * idx;
            int j  = jb + cc;
            float sc;
            if (j > i && j <= i + W_) sc = accv[idx] + bias_s[i + W_ - j];
            else                      sc = -1e30f;
            s_s[r][cc] = sc;
            pm = fmaxf(pm, sc);
        }
        red_s[r][g] = pm;
        __syncthreads();

        // phase 3: row max reduce (wave 0) + stage V chunk (all threads)
        if (tid < QT) {
            float mc = red_s[tid][0];
            #pragma unroll
            for (int t = 1; t < 8; ++t) mc = fmaxf(mc, red_s[tid][t]);
            float mo = m_s[tid];
            float mn = fmaxf(mo, mc);
            a_s[tid] = __expf(mo - mn);
            m_s[tid] = mn;
        }
        stage_kv(v, prev_v, b, n, h, jb, tid, kv_s);
        __syncthreads();

        // phase 4: exponentiate scores + partial sums; rescale O
        {
            float mn = m_s[r];
            float ps = 0.f;
            #pragma unroll
            for (int idx = 0; idx < 16; ++idx) {
                int cc = g + 8 * idx;
                float p = __expf(s_s[r][cc] - mn);
                s_s[r][cc] = p;
                ps += p;
            }
            red_s[r][g] = ps;
            float alpha = a_s[r];
            #pragma unroll
            for (int jj = 0; jj < 8; ++jj) o[jj] *= alpha;
        }
        __syncthreads();

        // phase 5: l update (wave 0) + PV accumulate (all threads)
        if (tid < QT) {
            float sum = red_s[tid][0];
            #pragma unroll
            for (int t = 1; t < 8; ++t) sum += red_s[tid][t];
            l_s[tid] = l_s[tid] * a_s[tid] + sum;
        }
        for (int cc = 0; cc < 128; ++cc) {
            float p  = s_s[r][cc];
            f32x4 va = *(const f32x4*)&kv_s[cc][d0];
            f32x4 vb = *(const f32x4*)&kv_s[cc][d0 + 4];
            o[0] += p * va[0]; o[1] += p * va[1]; o[2] += p * va[2]; o[3] += p * va[3];
            o[4] += p * vb[0]; o[5] += p * vb[1]; o[6] += p * vb[2]; o[7] += p * vb[3];
        }
        __syncthreads();
    }

    // epilogue: normalize and store
    float linv = 1.0f / l_s[r];
    float* dst = out + (((size_t)b * S_ + n * W_ + i) * H_ + h) * D_ + d0;
    f32x4 o0 = {o[0]*linv, o[1]*linv, o[2]*linv, o[3]*linv};
    f32x4 o1 = {o[4]*linv, o[5]*linv, o[6]*linv, o[7]*linv};
    *(f32x4*)(dst)     = o0;
    *(f32x4*)(dst + 4) = o1;
}

// ---------------------------------------------------------------------------
// next_k / next_v: copy last window of k and v into the output tail
// ---------------------------------------------------------------------------
__global__ void tail_kernel(const float* __restrict__ k, const float* __restrict__ v,
                            float* __restrict__ out)
{
    int t = blockIdx.x * 256 + threadIdx.x;      // 0..262143 float4 units
    int sec = t >> 17;                           // 0: k, 1: v (131072 f4 each)
    int t2  = t & 131071;
    int b   = t2 >> 16;                          // 65536 f4 per batch
    int rem = t2 & 65535;
    const float* base = sec ? v : k;
    size_t srcoff = (size_t)b * (S_ * H_ * D_) + (size_t)(S_ - W_) * H_ * D_ + (size_t)rem * 4;
    size_t dstoff = (size_t)B_ * S_ * H_ * D_ + (size_t)sec * (B_ * W_ * H_ * D_)
                  + (size_t)b * (W_ * H_ * D_) + (size_t)rem * 4;
    *(f32x4*)(out + dstoff) = *(const f32x4*)(base + srcoff);
}

extern "C" void kernel_launch(void* const* d_in, const int* in_sizes, int n_in,
                              void* d_out, int out_size, void* d_ws, size_t ws_size,
                              hipStream_t stream)
{
    const float* xs       = (const float*)d_in[0];
    const float* prev_k   = (const float*)d_in[1];
    const float* prev_v   = (const float*)d_in[2];
    const float* w_q      = (const float*)d_in[3];
    const float* w_k      = (const float*)d_in[4];
    const float* w_v      = (const float*)d_in[5];
    const float* rel_bias = (const float*)d_in[6];
    float* out = (float*)d_out;

    const size_t qkv_elems = (size_t)B_ * S_ * H_ * D_;  // 4,194,304
    float* q = (float*)d_ws;
    float* k = q + qkv_elems;
    float* v = k + qkv_elems;

    dim3 pgrid(64, 4);
    proj_kernel<<<pgrid, 256, 0, stream>>>(xs, w_q, q, 0.125f);
    proj_kernel<<<pgrid, 256, 0, stream>>>(xs, w_k, k, 1.0f);
    proj_kernel<<<pgrid, 256, 0, stream>>>(xs, w_v, v, 1.0f);

    attn_kernel<<<B_ * NW_ * H_ * (W_ / QT), 256, 0, stream>>>(
        q, k, v, prev_k, prev_v, rel_bias, out);

    tail_kernel<<<1024, 256, 0, stream>>>(k, v, out);
}

// Round 3
// 195.125 us; speedup vs baseline: 23.1263x; 23.1263x over previous
//
#include <hip/hip_runtime.h>
#include <hip/hip_bf16.h>
#include <math.h>

#define B_ 2
#define S_ 4096
#define E_ 512
#define H_ 8
#define D_ 64
#define W_ 512
#define NW_ 8

#define MASKV -1e30f
#define MINIT -1e4f

typedef float f32x4 __attribute__((ext_vector_type(4)));
typedef short s16x4 __attribute__((ext_vector_type(4)));
typedef short s16x8 __attribute__((ext_vector_type(8)));

__device__ inline short f2bf(float f) {
    unsigned u = __builtin_bit_cast(unsigned, f);
    unsigned r = (u + 0x7FFFu + ((u >> 16) & 1u)) >> 16;
    return (short)r;
}

__device__ inline s16x8 pack8(f32x4 a, f32x4 b) {
    s16x8 r;
    r[0]=f2bf(a[0]); r[1]=f2bf(a[1]); r[2]=f2bf(a[2]); r[3]=f2bf(a[3]);
    r[4]=f2bf(b[0]); r[5]=f2bf(b[1]); r[6]=f2bf(b[2]); r[7]=f2bf(b[3]);
    return r;
}

// ---------------------------------------------------------------------------
// Fused QKV projection: C_z[M=8192][N=512] = xs[M][K=512] * W_z[K][N] * scale_z
// 64x128 block tile, 256 threads (4 waves, each 64m x 32n), bf16 MFMA.
// ---------------------------------------------------------------------------
__global__ __launch_bounds__(256, 2)
void proj_kernel(const float* __restrict__ xs, const float* __restrict__ wq,
                 const float* __restrict__ wk, const float* __restrict__ wv,
                 float* __restrict__ qkv)
{
    __shared__ short As[64][40];    // [m][k]
    __shared__ short Bs[128][40];   // [n][k]

    const int z  = blockIdx.z;
    const float* Wg = (z == 0) ? wq : (z == 1) ? wk : wv;
    const float scale = (z == 0) ? 0.125f : 1.0f;
    float* C = qkv + (size_t)z * ((size_t)B_ * S_ * H_ * D_);

    const int tid = threadIdx.x;
    const int m0  = blockIdx.x * 64;
    const int n0  = blockIdx.y * 128;
    const int wave = tid >> 6, lane = tid & 63;
    const int wn  = wave * 32;
    const int lr  = lane & 15, quad = lane >> 4;

    f32x4 acc[4][2] = {};

    const int arow = tid >> 2, akseg = (tid & 3) * 8;
    const int krow = tid >> 3, nseg  = (tid & 7) * 16;

    for (int k0 = 0; k0 < 512; k0 += 32) {
        // A tile 64x32, coalesced
        {
            const float* src = xs + (size_t)(m0 + arow) * 512 + k0 + akseg;
            f32x4 x0 = *(const f32x4*)(src);
            f32x4 x1 = *(const f32x4*)(src + 4);
            *(s16x8*)&As[arow][akseg] = pack8(x0, x1);
        }
        // B tile 32k x 128n, coalesced reads along n, transpose into Bs[n][k]
        {
            const float* src = Wg + (size_t)(k0 + krow) * 512 + n0 + nseg;
            f32x4 w0 = *(const f32x4*)(src);
            f32x4 w1 = *(const f32x4*)(src + 4);
            f32x4 w2 = *(const f32x4*)(src + 8);
            f32x4 w3 = *(const f32x4*)(src + 12);
            float wv16[16] = {w0[0],w0[1],w0[2],w0[3], w1[0],w1[1],w1[2],w1[3],
                              w2[0],w2[1],w2[2],w2[3], w3[0],w3[1],w3[2],w3[3]};
            #pragma unroll
            for (int mm = 0; mm < 16; ++mm)
                Bs[nseg + mm][krow] = f2bf(wv16[mm]);
        }
        __syncthreads();

        s16x8 af[4], bf[2];
        #pragma unroll
        for (int tm = 0; tm < 4; ++tm)
            af[tm] = *(const s16x8*)&As[tm * 16 + lr][quad * 8];
        #pragma unroll
        for (int tn = 0; tn < 2; ++tn)
            bf[tn] = *(const s16x8*)&Bs[wn + tn * 16 + lr][quad * 8];
        #pragma unroll
        for (int tm = 0; tm < 4; ++tm)
            #pragma unroll
            for (int tn = 0; tn < 2; ++tn)
                acc[tm][tn] = __builtin_amdgcn_mfma_f32_16x16x32_bf16(
                    af[tm], bf[tn], acc[tm][tn], 0, 0, 0);
        __syncthreads();
    }

    #pragma unroll
    for (int tm = 0; tm < 4; ++tm)
        #pragma unroll
        for (int tn = 0; tn < 2; ++tn) {
            int col = n0 + wn + tn * 16 + lr;
            #pragma unroll
            for (int gg = 0; gg < 4; ++gg) {
                int row = m0 + tm * 16 + quad * 4 + gg;
                C[(size_t)row * 512 + col] = acc[tm][tn][gg] * scale;
            }
        }
}

// ---------------------------------------------------------------------------
// MFMA flash attention. Block = (b, window n, head h, 128 q rows).
// 4 waves x 32 q rows. Chunks of 64 keys. Online softmax in registers.
// ---------------------------------------------------------------------------
__global__ __launch_bounds__(256, 2)
void attn_kernel(const float* __restrict__ q, const float* __restrict__ k,
                 const float* __restrict__ v, const float* __restrict__ prev_k,
                 const float* __restrict__ prev_v, const float* __restrict__ rel_bias,
                 float* __restrict__ out)
{
    __shared__ short qp_s[128][72];   // Q staging, then per-wave P buffers
    __shared__ short k_s[64][72];     // [key][d]
    __shared__ short vt_s[64][72];    // [d][key]
    __shared__ float bias_s[512];

    const int bid = blockIdx.x;
    const int qt = bid & 3;
    const int h  = (bid >> 2) & 7;
    const int n  = (bid >> 5) & 7;
    const int b  = bid >> 8;
    const int tid = threadIdx.x;
    const int wave = tid >> 6, lane = tid & 63;
    const int lr = lane & 15, quad = lane >> 4;
    const int q0 = qt * 128;
    const int i0 = q0 + 32 * wave;

    // per-head T5 bias over distance nd = i + 512 - j, nd in [0,512)
    for (int nd = tid; nd < 512; nd += 256) {
        int bucket;
        if (nd < 16) bucket = nd;
        else {
            int vb = 16 + (int)(log((double)nd * (1.0 / 16.0)) * (16.0 / log(8.0)));
            bucket = vb < 31 ? vb : 31;
        }
        bias_s[nd] = rel_bias[h * 32 + bucket];
    }

    // Q staging: wave-local rows (thread tid stages row tid>>1, in own wave)
    {
        int row = tid >> 1, dh = (tid & 1) * 32;
        const float* src = q + (((size_t)b * S_ + n * W_ + q0 + row) * H_ + h) * D_ + dh;
        #pragma unroll
        for (int m = 0; m < 4; ++m) {
            f32x4 x0 = *(const f32x4*)(src + 8 * m);
            f32x4 x1 = *(const f32x4*)(src + 8 * m + 4);
            *(s16x8*)&qp_s[row][dh + 8 * m] = pack8(x0, x1);
        }
    }
    // Q A-frags (wave-local read-after-write)
    s16x8 aq[2][2];
    #pragma unroll
    for (int tm = 0; tm < 2; ++tm)
        #pragma unroll
        for (int ks = 0; ks < 2; ++ks)
            aq[tm][ks] = *(const s16x8*)&qp_s[32 * wave + tm * 16 + lr][ks * 32 + quad * 8];

    f32x4 oacc[2][4] = {};       // [tm][tn_d]
    float m_r[2][4], l_r[2][4];
    #pragma unroll
    for (int tm = 0; tm < 2; ++tm)
        #pragma unroll
        for (int rg = 0; rg < 4; ++rg) { m_r[tm][rg] = MINIT; l_r[tm][rg] = 0.f; }

    const int cmin = wave >> 1;
    const int cmax = 8 + (wave >> 1);

    const int srow = tid >> 2;            // 0..63: staged key row
    const int sdh  = (tid & 3) * 16;      // d segment

    for (int c = 0; c < 10; ++c) {
        __syncthreads();
        // ---- stage K[key][d] and V^T[d][key] for keys jj in [q0+64c, +64) ----
        // key jj < W comes from prev window: k[(n-1)W + jj] if n>0 else prev_k[jj]
        {
            int jj = q0 + 64 * c + srow;
            int p  = n * W_ + jj - W_;            // position in current k/v if >= 0
            const float* ksrc = (p >= 0)
                ? (k      + (((size_t)b * S_ + p) * H_ + h) * D_ + sdh)
                : (prev_k + (((size_t)b * W_ + jj) * H_ + h) * D_ + sdh);
            #pragma unroll
            for (int m = 0; m < 2; ++m) {
                f32x4 x0 = *(const f32x4*)(ksrc + 8 * m);
                f32x4 x1 = *(const f32x4*)(ksrc + 8 * m + 4);
                *(s16x8*)&k_s[srow][sdh + 8 * m] = pack8(x0, x1);
            }
            const float* vsrc = (p >= 0)
                ? (v      + (((size_t)b * S_ + p) * H_ + h) * D_ + sdh)
                : (prev_v + (((size_t)b * W_ + jj) * H_ + h) * D_ + sdh);
            #pragma unroll
            for (int m = 0; m < 4; ++m) {
                f32x4 x = *(const f32x4*)(vsrc + 4 * m);
                vt_s[sdh + 4 * m + 0][srow] = f2bf(x[0]);
                vt_s[sdh + 4 * m + 1][srow] = f2bf(x[1]);
                vt_s[sdh + 4 * m + 2][srow] = f2bf(x[2]);
                vt_s[sdh + 4 * m + 3][srow] = f2bf(x[3]);
            }
        }
        __syncthreads();
        if (c < cmin || c > cmax) continue;

        // ---- S = Q K^T (32 x 64 per wave) ----
        f32x4 sacc[2][4] = {};
        #pragma unroll
        for (int ks = 0; ks < 2; ++ks) {
            s16x8 bk[4];
            #pragma unroll
            for (int tn = 0; tn < 4; ++tn)
                bk[tn] = *(const s16x8*)&k_s[tn * 16 + lr][ks * 32 + quad * 8];
            #pragma unroll
            for (int tm = 0; tm < 2; ++tm)
                #pragma unroll
                for (int tn = 0; tn < 4; ++tn)
                    sacc[tm][tn] = __builtin_amdgcn_mfma_f32_16x16x32_bf16(
                        aq[tm][ks], bk[tn], sacc[tm][tn], 0, 0, 0);
        }

        // ---- bias + mask (C-layout: col = lr, row = quad*4+reg) ----
        const int jc = q0 + 64 * c + lr;
        #pragma unroll
        for (int tm = 0; tm < 2; ++tm)
            #pragma unroll
            for (int tn = 0; tn < 4; ++tn) {
                int j = jc + tn * 16;
                #pragma unroll
                for (int rg = 0; rg < 4; ++rg) {
                    int i = i0 + tm * 16 + quad * 4 + rg;
                    unsigned dm1 = (unsigned)(j - i - 1);
                    int nd = (i + 512 - j) & 511;
                    float sv = sacc[tm][tn][rg] + bias_s[nd];
                    sacc[tm][tn][rg] = (dm1 < 512u) ? sv : MASKV;
                }
            }

        // ---- row max across 4 tn + 16-lane butterfly ----
        float rmax[2][4];
        #pragma unroll
        for (int tm = 0; tm < 2; ++tm)
            #pragma unroll
            for (int rg = 0; rg < 4; ++rg)
                rmax[tm][rg] = fmaxf(fmaxf(sacc[tm][0][rg], sacc[tm][1][rg]),
                                     fmaxf(sacc[tm][2][rg], sacc[tm][3][rg]));
        #pragma unroll
        for (int off = 1; off < 16; off <<= 1)
            #pragma unroll
            for (int tm = 0; tm < 2; ++tm)
                #pragma unroll
                for (int rg = 0; rg < 4; ++rg)
                    rmax[tm][rg] = fmaxf(rmax[tm][rg], __shfl_xor(rmax[tm][rg], off));

        float al[2][4], rs[2][4];
        #pragma unroll
        for (int tm = 0; tm < 2; ++tm)
            #pragma unroll
            for (int rg = 0; rg < 4; ++rg) {
                float mo = m_r[tm][rg];
                float mn = fmaxf(mo, rmax[tm][rg]);
                al[tm][rg] = __expf(mo - mn);
                m_r[tm][rg] = mn;
                rs[tm][rg] = 0.f;
            }

        // ---- P = exp(S - m), write to wave-private LDS (bf16) ----
        #pragma unroll
        for (int tm = 0; tm < 2; ++tm)
            #pragma unroll
            for (int tn = 0; tn < 4; ++tn)
                #pragma unroll
                for (int rg = 0; rg < 4; ++rg) {
                    float p = __expf(sacc[tm][tn][rg] - m_r[tm][rg]);
                    rs[tm][rg] += p;
                    qp_s[32 * wave + tm * 16 + quad * 4 + rg][tn * 16 + lr] = f2bf(p);
                }

        #pragma unroll
        for (int off = 1; off < 16; off <<= 1)
            #pragma unroll
            for (int tm = 0; tm < 2; ++tm)
                #pragma unroll
                for (int rg = 0; rg < 4; ++rg)
                    rs[tm][rg] += __shfl_xor(rs[tm][rg], off);

        #pragma unroll
        for (int tm = 0; tm < 2; ++tm)
            #pragma unroll
            for (int rg = 0; rg < 4; ++rg)
                l_r[tm][rg] = l_r[tm][rg] * al[tm][rg] + rs[tm][rg];

        #pragma unroll
        for (int tm = 0; tm < 2; ++tm)
            #pragma unroll
            for (int tn = 0; tn < 4; ++tn)
                #pragma unroll
                for (int rg = 0; rg < 4; ++rg)
                    oacc[tm][tn][rg] *= al[tm][rg];

        // ensure this wave's P writes are visible to its own reads
        asm volatile("s_waitcnt lgkmcnt(0)" ::: "memory");

        // ---- O += P V ----
        #pragma unroll
        for (int ks = 0; ks < 2; ++ks) {
            s16x8 ap[2], bv[4];
            #pragma unroll
            for (int tm = 0; tm < 2; ++tm)
                ap[tm] = *(const s16x8*)&qp_s[32 * wave + tm * 16 + lr][ks * 32 + quad * 8];
            #pragma unroll
            for (int tn = 0; tn < 4; ++tn)
                bv[tn] = *(const s16x8*)&vt_s[tn * 16 + lr][ks * 32 + quad * 8];
            #pragma unroll
            for (int tm = 0; tm < 2; ++tm)
                #pragma unroll
                for (int tn = 0; tn < 4; ++tn)
                    oacc[tm][tn] = __builtin_amdgcn_mfma_f32_16x16x32_bf16(
                        ap[tm], bv[tn], oacc[tm][tn], 0, 0, 0);
        }
    }

    // ---- epilogue: normalize, store ----
    #pragma unroll
    for (int tm = 0; tm < 2; ++tm)
        #pragma unroll
        for (int rg = 0; rg < 4; ++rg) {
            int row = i0 + tm * 16 + quad * 4 + rg;
            float linv = 1.0f / l_r[tm][rg];
            float* dst = out + (((size_t)b * S_ + n * W_ + row) * H_ + h) * D_ + lr;
            #pragma unroll
            for (int tn = 0; tn < 4; ++tn)
                dst[tn * 16] = oacc[tm][tn][rg] * linv;
        }
}

// ---------------------------------------------------------------------------
// next_k / next_v: copy last window of k and v into the output tail
// ---------------------------------------------------------------------------
__global__ void tail_kernel(const float* __restrict__ k, const float* __restrict__ v,
                            float* __restrict__ out)
{
    int t = blockIdx.x * 256 + threadIdx.x;      // 262144 float4 units
    int sec = t >> 17;
    int t2  = t & 131071;
    int b   = t2 >> 16;
    int rem = t2 & 65535;
    const float* base = sec ? v : k;
    size_t srcoff = (size_t)b * (S_ * H_ * D_) + (size_t)(S_ - W_) * H_ * D_ + (size_t)rem * 4;
    size_t dstoff = (size_t)B_ * S_ * H_ * D_ + (size_t)sec * (B_ * W_ * H_ * D_)
                  + (size_t)b * (W_ * H_ * D_) + (size_t)rem * 4;
    *(f32x4*)(out + dstoff) = *(const f32x4*)(base + srcoff);
}

extern "C" void kernel_launch(void* const* d_in, const int* in_sizes, int n_in,
                              void* d_out, int out_size, void* d_ws, size_t ws_size,
                              hipStream_t stream)
{
    const float* xs       = (const float*)d_in[0];
    const float* prev_k   = (const float*)d_in[1];
    const float* prev_v   = (const float*)d_in[2];
    const float* w_q      = (const float*)d_in[3];
    const float* w_k      = (const float*)d_in[4];
    const float* w_v      = (const float*)d_in[5];
    const float* rel_bias = (const float*)d_in[6];
    float* out = (float*)d_out;

    const size_t qkv_elems = (size_t)B_ * S_ * H_ * D_;
    float* q = (float*)d_ws;
    float* k = q + qkv_elems;
    float* v = k + qkv_elems;

    dim3 pgrid(128, 4, 3);
    proj_kernel<<<pgrid, 256, 0, stream>>>(xs, w_q, w_k, w_v, (float*)d_ws);

    attn_kernel<<<512, 256, 0, stream>>>(q, k, v, prev_k, prev_v, rel_bias, out);

    tail_kernel<<<1024, 256, 0, stream>>>(k, v, out);
}

// Round 4
// 167.955 us; speedup vs baseline: 26.8675x; 1.1618x over previous
//
#include <hip/hip_runtime.h>
#include <hip/hip_bf16.h>
#include <math.h>

#define B_ 2
#define S_ 4096
#define E_ 512
#define H_ 8
#define D_ 64
#define W_ 512
#define NW_ 8

#define MASKV -1e30f
#define MINIT -1e4f

typedef float f32x4 __attribute__((ext_vector_type(4)));
typedef short s16x4 __attribute__((ext_vector_type(4)));
typedef short s16x8 __attribute__((ext_vector_type(8)));

__device__ inline short f2bf(float f) {
    unsigned u = __builtin_bit_cast(unsigned, f);
    unsigned r = (u + 0x7FFFu + ((u >> 16) & 1u)) >> 16;
    return (short)r;
}
__device__ inline float bf2f(short s) {
    unsigned u = ((unsigned)(unsigned short)s) << 16;
    return __builtin_bit_cast(float, u);
}
__device__ inline s16x8 pack8(f32x4 a, f32x4 b) {
    s16x8 r;
    r[0]=f2bf(a[0]); r[1]=f2bf(a[1]); r[2]=f2bf(a[2]); r[3]=f2bf(a[3]);
    r[4]=f2bf(b[0]); r[5]=f2bf(b[1]); r[6]=f2bf(b[2]); r[7]=f2bf(b[3]);
    return r;
}

// ---------------------------------------------------------------------------
// Pre-pass A: xs fp32 -> bf16
// ---------------------------------------------------------------------------
__global__ void convert_xs_kernel(const float* __restrict__ xs, short* __restrict__ xsbf)
{
    size_t i = ((size_t)blockIdx.x * 256 + threadIdx.x) * 8;
    f32x4 a = *(const f32x4*)(xs + i);
    f32x4 b = *(const f32x4*)(xs + i + 4);
    *(s16x8*)(xsbf + i) = pack8(a, b);
}

// ---------------------------------------------------------------------------
// Pre-pass B: wt[z*512 + n][k] = w_z[k][n] * (z==0 ? 0.125 : 1), bf16
// grid (8 k-tiles, 24 n-tiles over z*512+n), 64x64 tiles
// ---------------------------------------------------------------------------
__global__ void transpose_w_kernel(const float* __restrict__ wq, const float* __restrict__ wk,
                                   const float* __restrict__ wv, short* __restrict__ wt)
{
    __shared__ float st[64][68];
    const int k0 = blockIdx.x * 64;
    const int nt = blockIdx.y;            // 0..23
    const int z  = nt >> 3;
    const int n0 = (nt & 7) * 64;
    const float* wz = (z == 0) ? wq : (z == 1) ? wk : wv;
    const float scale = (z == 0) ? 0.125f : 1.0f;
    const int tid = threadIdx.x;

    {
        int kk = tid >> 4, nn = (tid & 15) * 4;
        #pragma unroll
        for (int it = 0; it < 4; ++it) {
            f32x4 x = *(const f32x4*)(wz + (size_t)(k0 + kk + it * 16) * 512 + n0 + nn);
            *(f32x4*)&st[kk + it * 16][nn] = x;
        }
    }
    __syncthreads();
    {
        int nn2 = tid >> 2, kseg = (tid & 3) * 16;
        s16x8 o0, o1;
        #pragma unroll
        for (int j = 0; j < 8; ++j) o0[j] = f2bf(st[kseg + j][nn2] * scale);
        #pragma unroll
        for (int j = 0; j < 8; ++j) o1[j] = f2bf(st[kseg + 8 + j][nn2] * scale);
        short* dst = wt + (size_t)(z * 512 + n0 + nn2) * 512 + k0 + kseg;
        *(s16x8*)(dst) = o0;
        *(s16x8*)(dst + 8) = o1;
    }
}

// ---------------------------------------------------------------------------
// Fused QKV projection: qkvbf[z][m][n] = xs[m][:] . wt[z*512+n][:]
// A-operand = weights, B-operand = xs  =>  C col (lane&15) = xs row,
// C row (quad*4+reg) = weight col -> packed 4-bf16 stores.
// 128(m) x 128(n) tiles, BK=64, 4 waves in 2x2.
// ---------------------------------------------------------------------------
__global__ __launch_bounds__(256, 3)
void proj_kernel(const short* __restrict__ xsbf, const short* __restrict__ wt,
                 short* __restrict__ qkvbf)
{
    __shared__ short Xs[128][72];   // [xs row][k]
    __shared__ short Ws[128][72];   // [w col n][k]

    const int tid = threadIdx.x;
    const int m0  = blockIdx.x * 128;       // xs rows
    const int n0  = blockIdx.y * 128;       // global wt row in [0,1536)
    const int z   = n0 >> 9;
    const int ln0 = n0 & 511;
    const int wave = tid >> 6, lane = tid & 63;
    const int wq = (wave & 1) * 64;         // weight-dim offset
    const int wx = (wave >> 1) * 64;        // xs-dim offset
    const int lr = lane & 15, quad = lane >> 4;

    f32x4 acc[4][4] = {};                   // [ta(weight)][tb(xs)]

    const int srow = tid >> 1, scs = (tid & 1) * 32;

    for (int k0 = 0; k0 < 512; k0 += 64) {
        {
            const short* sa = xsbf + (size_t)(m0 + srow) * 512 + k0 + scs;
            const short* sb = wt   + (size_t)(n0 + srow) * 512 + k0 + scs;
            #pragma unroll
            for (int m = 0; m < 4; ++m) {
                *(s16x8*)&Xs[srow][scs + 8 * m] = *(const s16x8*)(sa + 8 * m);
                *(s16x8*)&Ws[srow][scs + 8 * m] = *(const s16x8*)(sb + 8 * m);
            }
        }
        __syncthreads();
        #pragma unroll
        for (int ks = 0; ks < 2; ++ks) {
            s16x8 af[4], bf[4];
            #pragma unroll
            for (int ta = 0; ta < 4; ++ta)
                af[ta] = *(const s16x8*)&Ws[wq + ta * 16 + lr][ks * 32 + quad * 8];
            #pragma unroll
            for (int tb = 0; tb < 4; ++tb)
                bf[tb] = *(const s16x8*)&Xs[wx + tb * 16 + lr][ks * 32 + quad * 8];
            #pragma unroll
            for (int ta = 0; ta < 4; ++ta)
                #pragma unroll
                for (int tb = 0; tb < 4; ++tb)
                    acc[ta][tb] = __builtin_amdgcn_mfma_f32_16x16x32_bf16(
                        af[ta], bf[tb], acc[ta][tb], 0, 0, 0);
        }
        __syncthreads();
    }

    // store: C[m = xs row][n]: lane col lr = m-offset, rows = consecutive n
    short* base = qkvbf + (size_t)z * ((size_t)8192 * 512);
    #pragma unroll
    for (int ta = 0; ta < 4; ++ta)
        #pragma unroll
        for (int tb = 0; tb < 4; ++tb) {
            int m  = m0 + wx + tb * 16 + lr;
            int ln = ln0 + wq + ta * 16 + quad * 4;
            s16x4 o;
            o[0] = f2bf(acc[ta][tb][0]); o[1] = f2bf(acc[ta][tb][1]);
            o[2] = f2bf(acc[ta][tb][2]); o[3] = f2bf(acc[ta][tb][3]);
            *(s16x4*)(base + (size_t)m * 512 + ln) = o;
        }
}

// ---------------------------------------------------------------------------
// MFMA flash attention. Block = (b, window n, head h, 128 q rows).
// bf16 q/k/v inputs; prev_k/prev_v fp32.
// ---------------------------------------------------------------------------
__global__ __launch_bounds__(256, 2)
void attn_kernel(const short* __restrict__ qkvbf, const float* __restrict__ prev_k,
                 const float* __restrict__ prev_v, const float* __restrict__ rel_bias,
                 float* __restrict__ out)
{
    __shared__ short qp_s[128][72];   // Q staging, then per-wave P buffers
    __shared__ short k_s[64][72];     // [key][d]
    __shared__ short vt_s[64][72];    // [d][key]
    __shared__ float bias_s[512];

    const short* qb = qkvbf;
    const short* kb = qkvbf + (size_t)8192 * 512;
    const short* vb = qkvbf + (size_t)2 * 8192 * 512;

    const int bid = blockIdx.x;
    const int qt = bid & 3;
    const int h  = (bid >> 2) & 7;
    const int n  = (bid >> 5) & 7;
    const int b  = bid >> 8;
    const int tid = threadIdx.x;
    const int wave = tid >> 6, lane = tid & 63;
    const int lr = lane & 15, quad = lane >> 4;
    const int q0 = qt * 128;
    const int i0 = q0 + 32 * wave;

    for (int nd = tid; nd < 512; nd += 256) {
        int bucket;
        if (nd < 16) bucket = nd;
        else {
            int vbk = 16 + (int)(log((double)nd * (1.0 / 16.0)) * (16.0 / log(8.0)));
            bucket = vbk < 31 ? vbk : 31;
        }
        bias_s[nd] = rel_bias[h * 32 + bucket];
    }

    // Q staging: bf16 direct copy
    {
        int row = tid >> 1, cs = (tid & 1) * 32;
        const short* src = qb + (size_t)(b * S_ + n * W_ + q0 + row) * 512 + h * 64 + cs;
        *(s16x8*)&qp_s[row][cs]     = *(const s16x8*)(src);
        *(s16x8*)&qp_s[row][cs + 8] = *(const s16x8*)(src + 8);
        *(s16x8*)&qp_s[row][cs + 16] = *(const s16x8*)(src + 16);
        *(s16x8*)&qp_s[row][cs + 24] = *(const s16x8*)(src + 24);
    }
    s16x8 aq[2][2];
    #pragma unroll
    for (int tm = 0; tm < 2; ++tm)
        #pragma unroll
        for (int ks = 0; ks < 2; ++ks)
            aq[tm][ks] = *(const s16x8*)&qp_s[32 * wave + tm * 16 + lr][ks * 32 + quad * 8];

    f32x4 oacc[2][4] = {};
    float m_r[2][4], l_r[2][4];
    #pragma unroll
    for (int tm = 0; tm < 2; ++tm)
        #pragma unroll
        for (int rg = 0; rg < 4; ++rg) { m_r[tm][rg] = MINIT; l_r[tm][rg] = 0.f; }

    const int cmin = wave >> 1;
    const int cmax = 8 + (wave >> 1);

    const int ksr = tid >> 2;             // K staging: key row 0..63
    const int ksd = (tid & 3) * 16;       // K staging: d segment
    const int vkey = tid & 63;            // V staging: key = lane
    const int vd0 = (tid >> 6) * 16;      // V staging: 16 d-rows per wave

    for (int c = 0; c < 10; ++c) {
        __syncthreads();
        // ---- stage K[key][d] ----
        {
            int jj = q0 + 64 * c + ksr;
            int p  = n * W_ + jj - W_;
            if (p >= 0) {
                const short* src = kb + (size_t)(b * S_ + p) * 512 + h * 64 + ksd;
                *(s16x8*)&k_s[ksr][ksd]     = *(const s16x8*)(src);
                *(s16x8*)&k_s[ksr][ksd + 8] = *(const s16x8*)(src + 8);
            } else {
                const float* src = prev_k + (((size_t)b * W_ + jj) * H_ + h) * D_ + ksd;
                f32x4 x0 = *(const f32x4*)(src);
                f32x4 x1 = *(const f32x4*)(src + 4);
                f32x4 x2 = *(const f32x4*)(src + 8);
                f32x4 x3 = *(const f32x4*)(src + 12);
                *(s16x8*)&k_s[ksr][ksd]     = pack8(x0, x1);
                *(s16x8*)&k_s[ksr][ksd + 8] = pack8(x2, x3);
            }
        }
        // ---- stage V^T[d][key]: conflict-free 2B writes (32 banks, 2-way sub-word) ----
        {
            int jj = q0 + 64 * c + vkey;
            int p  = n * W_ + jj - W_;
            s16x8 a0, a1;
            if (p >= 0) {
                const short* src = vb + (size_t)(b * S_ + p) * 512 + h * 64 + vd0;
                a0 = *(const s16x8*)(src);
                a1 = *(const s16x8*)(src + 8);
            } else {
                const float* src = prev_v + (((size_t)b * W_ + jj) * H_ + h) * D_ + vd0;
                f32x4 x0 = *(const f32x4*)(src);
                f32x4 x1 = *(const f32x4*)(src + 4);
                f32x4 x2 = *(const f32x4*)(src + 8);
                f32x4 x3 = *(const f32x4*)(src + 12);
                a0 = pack8(x0, x1);
                a1 = pack8(x2, x3);
            }
            #pragma unroll
            for (int m = 0; m < 8; ++m) vt_s[vd0 + m][vkey] = a0[m];
            #pragma unroll
            for (int m = 0; m < 8; ++m) vt_s[vd0 + 8 + m][vkey] = a1[m];
        }
        __syncthreads();
        if (c < cmin || c > cmax) continue;

        // ---- S = Q K^T ----
        f32x4 sacc[2][4] = {};
        #pragma unroll
        for (int ks = 0; ks < 2; ++ks) {
            s16x8 bk[4];
            #pragma unroll
            for (int tn = 0; tn < 4; ++tn)
                bk[tn] = *(const s16x8*)&k_s[tn * 16 + lr][ks * 32 + quad * 8];
            #pragma unroll
            for (int tm = 0; tm < 2; ++tm)
                #pragma unroll
                for (int tn = 0; tn < 4; ++tn)
                    sacc[tm][tn] = __builtin_amdgcn_mfma_f32_16x16x32_bf16(
                        aq[tm][ks], bk[tn], sacc[tm][tn], 0, 0, 0);
        }

        // ---- bias + mask ----
        const int jc = q0 + 64 * c + lr;
        #pragma unroll
        for (int tm = 0; tm < 2; ++tm)
            #pragma unroll
            for (int tn = 0; tn < 4; ++tn) {
                int j = jc + tn * 16;
                #pragma unroll
                for (int rg = 0; rg < 4; ++rg) {
                    int i = i0 + tm * 16 + quad * 4 + rg;
                    unsigned dm1 = (unsigned)(j - i - 1);
                    int nd = (i + 512 - j) & 511;
                    float sv = sacc[tm][tn][rg] + bias_s[nd];
                    sacc[tm][tn][rg] = (dm1 < 512u) ? sv : MASKV;
                }
            }

        // ---- online softmax ----
        float rmax[2][4];
        #pragma unroll
        for (int tm = 0; tm < 2; ++tm)
            #pragma unroll
            for (int rg = 0; rg < 4; ++rg)
                rmax[tm][rg] = fmaxf(fmaxf(sacc[tm][0][rg], sacc[tm][1][rg]),
                                     fmaxf(sacc[tm][2][rg], sacc[tm][3][rg]));
        #pragma unroll
        for (int off = 1; off < 16; off <<= 1)
            #pragma unroll
            for (int tm = 0; tm < 2; ++tm)
                #pragma unroll
                for (int rg = 0; rg < 4; ++rg)
                    rmax[tm][rg] = fmaxf(rmax[tm][rg], __shfl_xor(rmax[tm][rg], off));

        float al[2][4], rs[2][4];
        #pragma unroll
        for (int tm = 0; tm < 2; ++tm)
            #pragma unroll
            for (int rg = 0; rg < 4; ++rg) {
                float mo = m_r[tm][rg];
                float mn = fmaxf(mo, rmax[tm][rg]);
                al[tm][rg] = __expf(mo - mn);
                m_r[tm][rg] = mn;
                rs[tm][rg] = 0.f;
            }

        #pragma unroll
        for (int tm = 0; tm < 2; ++tm)
            #pragma unroll
            for (int tn = 0; tn < 4; ++tn)
                #pragma unroll
                for (int rg = 0; rg < 4; ++rg) {
                    float p = __expf(sacc[tm][tn][rg] - m_r[tm][rg]);
                    rs[tm][rg] += p;
                    qp_s[32 * wave + tm * 16 + quad * 4 + rg][tn * 16 + lr] = f2bf(p);
                }

        #pragma unroll
        for (int off = 1; off < 16; off <<= 1)
            #pragma unroll
            for (int tm = 0; tm < 2; ++tm)
                #pragma unroll
                for (int rg = 0; rg < 4; ++rg)
                    rs[tm][rg] += __shfl_xor(rs[tm][rg], off);

        #pragma unroll
        for (int tm = 0; tm < 2; ++tm)
            #pragma unroll
            for (int rg = 0; rg < 4; ++rg)
                l_r[tm][rg] = l_r[tm][rg] * al[tm][rg] + rs[tm][rg];

        #pragma unroll
        for (int tm = 0; tm < 2; ++tm)
            #pragma unroll
            for (int tn = 0; tn < 4; ++tn)
                #pragma unroll
                for (int rg = 0; rg < 4; ++rg)
                    oacc[tm][tn][rg] *= al[tm][rg];

        asm volatile("s_waitcnt lgkmcnt(0)" ::: "memory");

        // ---- O += P V ----
        #pragma unroll
        for (int ks = 0; ks < 2; ++ks) {
            s16x8 ap[2], bv[4];
            #pragma unroll
            for (int tm = 0; tm < 2; ++tm)
                ap[tm] = *(const s16x8*)&qp_s[32 * wave + tm * 16 + lr][ks * 32 + quad * 8];
            #pragma unroll
            for (int tn = 0; tn < 4; ++tn)
                bv[tn] = *(const s16x8*)&vt_s[tn * 16 + lr][ks * 32 + quad * 8];
            #pragma unroll
            for (int tm = 0; tm < 2; ++tm)
                #pragma unroll
                for (int tn = 0; tn < 4; ++tn)
                    oacc[tm][tn] = __builtin_amdgcn_mfma_f32_16x16x32_bf16(
                        ap[tm], bv[tn], oacc[tm][tn], 0, 0, 0);
        }
    }

    #pragma unroll
    for (int tm = 0; tm < 2; ++tm)
        #pragma unroll
        for (int rg = 0; rg < 4; ++rg) {
            int row = i0 + tm * 16 + quad * 4 + rg;
            float linv = 1.0f / l_r[tm][rg];
            float* dst = out + (((size_t)b * S_ + n * W_ + row) * H_ + h) * D_ + lr;
            #pragma unroll
            for (int tn = 0; tn < 4; ++tn)
                dst[tn * 16] = oacc[tm][tn][rg] * linv;
        }
}

// ---------------------------------------------------------------------------
// next_k / next_v: bf16 k/v last window -> fp32 output tail
// ---------------------------------------------------------------------------
__global__ void tail_kernel(const short* __restrict__ qkvbf, float* __restrict__ out)
{
    size_t idx8 = ((size_t)blockIdx.x * 256 + threadIdx.x) * 8;
    int sec = (int)(idx8 >> 19);
    int b   = (int)((idx8 >> 18) & 1);
    int r   = (int)((idx8 >> 9) & 511);
    int c   = (int)(idx8 & 511);
    const short* src = qkvbf + (size_t)(1 + sec) * 8192 * 512
                     + (size_t)(b * S_ + S_ - W_ + r) * 512 + c;
    s16x8 x = *(const s16x8*)src;
    f32x4 o0 = {bf2f(x[0]), bf2f(x[1]), bf2f(x[2]), bf2f(x[3])};
    f32x4 o1 = {bf2f(x[4]), bf2f(x[5]), bf2f(x[6]), bf2f(x[7])};
    float* dst = out + (size_t)B_ * S_ * H_ * D_ + (size_t)sec * (B_ * W_ * H_ * D_)
               + (size_t)(b * W_ + r) * 512 + c;
    *(f32x4*)(dst)     = o0;
    *(f32x4*)(dst + 4) = o1;
}

extern "C" void kernel_launch(void* const* d_in, const int* in_sizes, int n_in,
                              void* d_out, int out_size, void* d_ws, size_t ws_size,
                              hipStream_t stream)
{
    const float* xs       = (const float*)d_in[0];
    const float* prev_k   = (const float*)d_in[1];
    const float* prev_v   = (const float*)d_in[2];
    const float* w_q      = (const float*)d_in[3];
    const float* w_k      = (const float*)d_in[4];
    const float* w_v      = (const float*)d_in[5];
    const float* rel_bias = (const float*)d_in[6];
    float* out = (float*)d_out;

    short* xsbf  = (short*)d_ws;                       // 8192*512
    short* wt    = xsbf + (size_t)8192 * 512;          // 1536*512
    short* qkvbf = wt + (size_t)1536 * 512;            // 3*8192*512

    convert_xs_kernel<<<2048, 256, 0, stream>>>(xs, xsbf);
    transpose_w_kernel<<<dim3(8, 24), 256, 0, stream>>>(w_q, w_k, w_v, wt);

    proj_kernel<<<dim3(64, 12), 256, 0, stream>>>(xsbf, wt, qkvbf);

    attn_kernel<<<512, 256, 0, stream>>>(qkvbf, prev_k, prev_v, rel_bias, out);

    tail_kernel<<<512, 256, 0, stream>>>(qkvbf, out);
}

// Round 5
// 150.776 us; speedup vs baseline: 29.9287x; 1.1139x over previous
//
#include <hip/hip_runtime.h>
#include <hip/hip_bf16.h>
#include <math.h>

#define B_ 2
#define S_ 4096
#define E_ 512
#define H_ 8
#define D_ 64
#define W_ 512
#define NW_ 8

#define MASKV -1e30f
#define MINIT -1e4f

typedef float f32x4 __attribute__((ext_vector_type(4)));
typedef short s16x4 __attribute__((ext_vector_type(4)));
typedef short s16x8 __attribute__((ext_vector_type(8)));
typedef unsigned int u32;
typedef __attribute__((address_space(1))) const u32 as1_u32;
typedef __attribute__((address_space(3))) u32 as3_u32;

__device__ inline short f2bf(float f) {
    unsigned u = __builtin_bit_cast(unsigned, f);
    unsigned r = (u + 0x7FFFu + ((u >> 16) & 1u)) >> 16;
    return (short)r;
}
__device__ inline s16x8 pack8(f32x4 a, f32x4 b) {
    s16x8 r;
    r[0]=f2bf(a[0]); r[1]=f2bf(a[1]); r[2]=f2bf(a[2]); r[3]=f2bf(a[3]);
    r[4]=f2bf(b[0]); r[5]=f2bf(b[1]); r[6]=f2bf(b[2]); r[7]=f2bf(b[3]);
    return r;
}
// async global->LDS, 16B per lane; LDS dest = wave-uniform base + lane*16
__device__ __forceinline__ void gl_lds16(const void* g, void* l) {
    __builtin_amdgcn_global_load_lds((as1_u32*)(unsigned long long)g,
                                     (as3_u32*)(u32)(unsigned long long)l,
                                     16, 0, 0);
}

// ---------------------------------------------------------------------------
// Pre-pass: xs, prev_k, prev_v fp32 -> bf16
// ---------------------------------------------------------------------------
__global__ void convert_kernel(const float* __restrict__ xs, const float* __restrict__ pk,
                               const float* __restrict__ pv, short* __restrict__ xsbf,
                               short* __restrict__ pkbf, short* __restrict__ pvbf)
{
    size_t i8 = ((size_t)blockIdx.x * 256 + threadIdx.x) * 8;
    const float* src; short* dst; size_t off;
    if (i8 < 4194304)            { src = xs; dst = xsbf; off = i8; }
    else if (i8 < 4194304+524288){ src = pk; dst = pkbf; off = i8 - 4194304; }
    else                         { src = pv; dst = pvbf; off = i8 - 4194304 - 524288; }
    f32x4 a = *(const f32x4*)(src + off);
    f32x4 b = *(const f32x4*)(src + off + 4);
    *(s16x8*)(dst + off) = pack8(a, b);
}

// ---------------------------------------------------------------------------
// Pre-pass: wt[z*512 + n][k] = w_z[k][n] * (z==0 ? 0.125 : 1), bf16
// ---------------------------------------------------------------------------
__global__ void transpose_w_kernel(const float* __restrict__ wq, const float* __restrict__ wk,
                                   const float* __restrict__ wv, short* __restrict__ wt)
{
    __shared__ float st[64][68];
    const int k0 = blockIdx.x * 64;
    const int nt = blockIdx.y;
    const int z  = nt >> 3;
    const int n0 = (nt & 7) * 64;
    const float* wz = (z == 0) ? wq : (z == 1) ? wk : wv;
    const float scale = (z == 0) ? 0.125f : 1.0f;
    const int tid = threadIdx.x;
    {
        int kk = tid >> 4, nn = (tid & 15) * 4;
        #pragma unroll
        for (int it = 0; it < 4; ++it) {
            f32x4 x = *(const f32x4*)(wz + (size_t)(k0 + kk + it * 16) * 512 + n0 + nn);
            *(f32x4*)&st[kk + it * 16][nn] = x;
        }
    }
    __syncthreads();
    {
        int nn2 = tid >> 2, kseg = (tid & 3) * 16;
        s16x8 o0, o1;
        #pragma unroll
        for (int j = 0; j < 8; ++j) o0[j] = f2bf(st[kseg + j][nn2] * scale);
        #pragma unroll
        for (int j = 0; j < 8; ++j) o1[j] = f2bf(st[kseg + 8 + j][nn2] * scale);
        short* dst = wt + (size_t)(z * 512 + n0 + nn2) * 512 + k0 + kseg;
        *(s16x8*)(dst) = o0;
        *(s16x8*)(dst + 8) = o1;
    }
}

// ---------------------------------------------------------------------------
// Fused QKV projection, global_load_lds staging + XOR-granule swizzle.
// 128(m) x 128(n) tiles, BK=64. Epilogue also writes next_k/next_v (fp32).
// ---------------------------------------------------------------------------
__global__ __launch_bounds__(256, 4)
void proj_kernel(const short* __restrict__ xsbf, const short* __restrict__ wt,
                 short* __restrict__ qkvbf, float* __restrict__ out)
{
    __shared__ short Xs[128][64];   // [xs row][k], 128B rows, swizzled granules
    __shared__ short Ws[128][64];   // [w col n][k]

    const int tid = threadIdx.x;
    const int m0  = blockIdx.x * 128;
    const int n0  = blockIdx.y * 128;        // 0..1536
    const int z   = n0 >> 9;
    const int ln0 = n0 & 511;
    const int wave = tid >> 6, lane = tid & 63;
    const int wq = (wave & 1) * 64;
    const int wx = (wave >> 1) * 64;
    const int lr = lane & 15, quad = lane >> 4;

    f32x4 acc[4][4] = {};

    const int r8  = lane >> 3;     // 0..7 row within 8-row group
    const int gr  = lane & 7;      // physical granule (16B)

    for (int k0 = 0; k0 < 512; k0 += 64) {
        #pragma unroll
        for (int i = 0; i < 4; ++i) {
            int row = 32 * wave + 8 * i + r8;
            int gs  = gr ^ (row & 7);                    // swizzled source granule
            gl_lds16(xsbf + (size_t)(m0 + row) * 512 + k0 + gs * 8, &Xs[32 * wave + 8 * i][0]);
            gl_lds16(wt   + (size_t)(n0 + row) * 512 + k0 + gs * 8, &Ws[32 * wave + 8 * i][0]);
        }
        __syncthreads();
        #pragma unroll
        for (int ks = 0; ks < 2; ++ks) {
            s16x8 af[4], bf[4];
            #pragma unroll
            for (int ta = 0; ta < 4; ++ta) {
                int R = wq + ta * 16 + lr;
                af[ta] = *(const s16x8*)&Ws[R][(((ks * 4 + quad) ^ (R & 7)) * 8)];
            }
            #pragma unroll
            for (int tb = 0; tb < 4; ++tb) {
                int R = wx + tb * 16 + lr;
                bf[tb] = *(const s16x8*)&Xs[R][(((ks * 4 + quad) ^ (R & 7)) * 8)];
            }
            #pragma unroll
            for (int ta = 0; ta < 4; ++ta)
                #pragma unroll
                for (int tb = 0; tb < 4; ++tb)
                    acc[ta][tb] = __builtin_amdgcn_mfma_f32_16x16x32_bf16(
                        af[ta], bf[tb], acc[ta][tb], 0, 0, 0);
        }
        __syncthreads();
    }

    short* base = qkvbf + (size_t)z * ((size_t)8192 * 512);
    #pragma unroll
    for (int ta = 0; ta < 4; ++ta)
        #pragma unroll
        for (int tb = 0; tb < 4; ++tb) {
            int m  = m0 + wx + tb * 16 + lr;
            int ln = ln0 + wq + ta * 16 + quad * 4;
            s16x4 o;
            o[0] = f2bf(acc[ta][tb][0]); o[1] = f2bf(acc[ta][tb][1]);
            o[2] = f2bf(acc[ta][tb][2]); o[3] = f2bf(acc[ta][tb][3]);
            *(s16x4*)(base + (size_t)m * 512 + ln) = o;
            // fused next_k / next_v tail (fp32, straight from accumulator)
            if (z != 0 && (m & 4095) >= 3584) {
                int bb = m >> 12, rr = (m & 4095) - 3584;
                float* dst = out + 4194304 + (size_t)(z - 1) * 524288
                           + ((size_t)(bb * 512 + rr)) * 512 + ln;
                *(f32x4*)dst = acc[ta][tb];
            }
        }
}

// ---------------------------------------------------------------------------
// MFMA flash attention, double-buffered K/V LDS + register prefetch.
// Block = (b, window n, head h, 128 q rows); 1 barrier per 64-key chunk.
// ---------------------------------------------------------------------------
__global__ __launch_bounds__(256, 2)
void attn_kernel(const short* __restrict__ qkvbf, const short* __restrict__ pkbf,
                 const short* __restrict__ pvbf, const float* __restrict__ rel_bias,
                 float* __restrict__ out)
{
    __shared__ short qp_s[128][72];      // Q staging, then per-wave P buffers
    __shared__ short k_s[2][64][72];     // [buf][key][d]
    __shared__ short vt_s[2][64][72];    // [buf][d][key]
    __shared__ float bias_s[512];

    const short* qb = qkvbf;
    const short* kb = qkvbf + (size_t)8192 * 512;
    const short* vb = qkvbf + (size_t)2 * 8192 * 512;

    const int bid = blockIdx.x;
    const int qt = bid & 3;
    const int h  = (bid >> 2) & 7;
    const int n  = (bid >> 5) & 7;
    const int b  = bid >> 8;
    const int tid = threadIdx.x;
    const int wave = tid >> 6, lane = tid & 63;
    const int lr = lane & 15, quad = lane >> 4;
    const int q0 = qt * 128;
    const int i0 = q0 + 32 * wave;

    for (int nd = tid; nd < 512; nd += 256) {
        int bucket;
        if (nd < 16) bucket = nd;
        else {
            int vbk = 16 + (int)(log((double)nd * (1.0 / 16.0)) * (16.0 / log(8.0)));
            bucket = vbk < 31 ? vbk : 31;
        }
        bias_s[nd] = rel_bias[h * 32 + bucket];
    }

    // Q staging: wave-local rows
    {
        int row = tid >> 1, cs = (tid & 1) * 32;
        const short* src = qb + (size_t)(b * S_ + n * W_ + q0 + row) * 512 + h * 64 + cs;
        *(s16x8*)&qp_s[row][cs]      = *(const s16x8*)(src);
        *(s16x8*)&qp_s[row][cs + 8]  = *(const s16x8*)(src + 8);
        *(s16x8*)&qp_s[row][cs + 16] = *(const s16x8*)(src + 16);
        *(s16x8*)&qp_s[row][cs + 24] = *(const s16x8*)(src + 24);
    }
    s16x8 aq[2][2];
    #pragma unroll
    for (int tm = 0; tm < 2; ++tm)
        #pragma unroll
        for (int ks = 0; ks < 2; ++ks)
            aq[tm][ks] = *(const s16x8*)&qp_s[32 * wave + tm * 16 + lr][ks * 32 + quad * 8];

    f32x4 oacc[2][4] = {};
    float m_r[2][4], l_r[2][4];
    #pragma unroll
    for (int tm = 0; tm < 2; ++tm)
        #pragma unroll
        for (int rg = 0; rg < 4; ++rg) { m_r[tm][rg] = MINIT; l_r[tm][rg] = 0.f; }

    const int cmin = wave >> 1;
    const int cmax = 8 + (wave >> 1);

    const int ksr = tid >> 2;             // K staging: key row 0..63
    const int ksd = (tid & 3) * 16;       // K staging: d segment (shorts)
    const int vkey = tid & 63;            // V staging: key = lane
    const int vd0 = (tid >> 6) * 16;      // V staging: 16 d-rows per wave

    // ---- prefetch chunk 0 ----
    s16x8 rk0, rk1, rv0, rv1;
    {
        int jj = q0 + ksr;
        int p  = n * W_ + jj - W_;
        const short* ks = (p >= 0) ? kb + (size_t)(b * S_ + p) * 512 + h * 64 + ksd
                                   : pkbf + ((size_t)(b * W_ + jj) * H_ + h) * D_ + ksd;
        rk0 = *(const s16x8*)ks; rk1 = *(const s16x8*)(ks + 8);
        int jv = q0 + vkey;
        int pv = n * W_ + jv - W_;
        const short* vs = (pv >= 0) ? vb + (size_t)(b * S_ + pv) * 512 + h * 64 + vd0
                                    : pvbf + ((size_t)(b * W_ + jv) * H_ + h) * D_ + vd0;
        rv0 = *(const s16x8*)vs; rv1 = *(const s16x8*)(vs + 8);
    }

    for (int c = 0; c < 10; ++c) {
        const int pb = c & 1;
        // ---- write prefetched chunk into LDS buffer pb ----
        *(s16x8*)&k_s[pb][ksr][ksd]     = rk0;
        *(s16x8*)&k_s[pb][ksr][ksd + 8] = rk1;
        #pragma unroll
        for (int m = 0; m < 8; ++m) vt_s[pb][vd0 + m][vkey] = rv0[m];
        #pragma unroll
        for (int m = 0; m < 8; ++m) vt_s[pb][vd0 + 8 + m][vkey] = rv1[m];

        // ---- issue prefetch for next chunk (overlaps compute below) ----
        {
            int cn = (c < 9) ? c + 1 : 9;
            int jj = q0 + 64 * cn + ksr;
            int p  = n * W_ + jj - W_;
            const short* ks = (p >= 0) ? kb + (size_t)(b * S_ + p) * 512 + h * 64 + ksd
                                       : pkbf + ((size_t)(b * W_ + jj) * H_ + h) * D_ + ksd;
            rk0 = *(const s16x8*)ks; rk1 = *(const s16x8*)(ks + 8);
            int jv = q0 + 64 * cn + vkey;
            int pv = n * W_ + jv - W_;
            const short* vs = (pv >= 0) ? vb + (size_t)(b * S_ + pv) * 512 + h * 64 + vd0
                                        : pvbf + ((size_t)(b * W_ + jv) * H_ + h) * D_ + vd0;
            rv0 = *(const s16x8*)vs; rv1 = *(const s16x8*)(vs + 8);
        }

        __syncthreads();
        if (c < cmin || c > cmax) continue;

        // ---- S = Q K^T ----
        f32x4 sacc[2][4] = {};
        #pragma unroll
        for (int ks = 0; ks < 2; ++ks) {
            s16x8 bk[4];
            #pragma unroll
            for (int tn = 0; tn < 4; ++tn)
                bk[tn] = *(const s16x8*)&k_s[pb][tn * 16 + lr][ks * 32 + quad * 8];
            #pragma unroll
            for (int tm = 0; tm < 2; ++tm)
                #pragma unroll
                for (int tn = 0; tn < 4; ++tn)
                    sacc[tm][tn] = __builtin_amdgcn_mfma_f32_16x16x32_bf16(
                        aq[tm][ks], bk[tn], sacc[tm][tn], 0, 0, 0);
        }

        // ---- bias + mask (C-layout: col=lr is key, row=quad*4+rg is q) ----
        const int jc = q0 + 64 * c + lr;
        #pragma unroll
        for (int tm = 0; tm < 2; ++tm)
            #pragma unroll
            for (int tn = 0; tn < 4; ++tn) {
                int j = jc + tn * 16;
                #pragma unroll
                for (int rg = 0; rg < 4; ++rg) {
                    int i = i0 + tm * 16 + quad * 4 + rg;
                    unsigned dm1 = (unsigned)(j - i - 1);
                    int nd = (i + 512 - j) & 511;
                    float sv = sacc[tm][tn][rg] + bias_s[nd];
                    sacc[tm][tn][rg] = (dm1 < 512u) ? sv : MASKV;
                }
            }

        // ---- online softmax ----
        float rmax[2][4];
        #pragma unroll
        for (int tm = 0; tm < 2; ++tm)
            #pragma unroll
            for (int rg = 0; rg < 4; ++rg)
                rmax[tm][rg] = fmaxf(fmaxf(sacc[tm][0][rg], sacc[tm][1][rg]),
                                     fmaxf(sacc[tm][2][rg], sacc[tm][3][rg]));
        #pragma unroll
        for (int off = 1; off < 16; off <<= 1)
            #pragma unroll
            for (int tm = 0; tm < 2; ++tm)
                #pragma unroll
                for (int rg = 0; rg < 4; ++rg)
                    rmax[tm][rg] = fmaxf(rmax[tm][rg], __shfl_xor(rmax[tm][rg], off));

        float al[2][4], rs[2][4];
        #pragma unroll
        for (int tm = 0; tm < 2; ++tm)
            #pragma unroll
            for (int rg = 0; rg < 4; ++rg) {
                float mo = m_r[tm][rg];
                float mn = fmaxf(mo, rmax[tm][rg]);
                al[tm][rg] = __expf(mo - mn);
                m_r[tm][rg] = mn;
                rs[tm][rg] = 0.f;
            }

        #pragma unroll
        for (int tm = 0; tm < 2; ++tm)
            #pragma unroll
            for (int tn = 0; tn < 4; ++tn)
                #pragma unroll
                for (int rg = 0; rg < 4; ++rg) {
                    float p = __expf(sacc[tm][tn][rg] - m_r[tm][rg]);
                    rs[tm][rg] += p;
                    qp_s[32 * wave + tm * 16 + quad * 4 + rg][tn * 16 + lr] = f2bf(p);
                }

        #pragma unroll
        for (int off = 1; off < 16; off <<= 1)
            #pragma unroll
            for (int tm = 0; tm < 2; ++tm)
                #pragma unroll
                for (int rg = 0; rg < 4; ++rg)
                    rs[tm][rg] += __shfl_xor(rs[tm][rg], off);

        #pragma unroll
        for (int tm = 0; tm < 2; ++tm)
            #pragma unroll
            for (int rg = 0; rg < 4; ++rg)
                l_r[tm][rg] = l_r[tm][rg] * al[tm][rg] + rs[tm][rg];

        #pragma unroll
        for (int tm = 0; tm < 2; ++tm)
            #pragma unroll
            for (int tn = 0; tn < 4; ++tn)
                #pragma unroll
                for (int rg = 0; rg < 4; ++rg)
                    oacc[tm][tn][rg] *= al[tm][rg];

        asm volatile("s_waitcnt lgkmcnt(0)" ::: "memory");

        // ---- O += P V ----
        #pragma unroll
        for (int ks = 0; ks < 2; ++ks) {
            s16x8 ap[2], bv[4];
            #pragma unroll
            for (int tm = 0; tm < 2; ++tm)
                ap[tm] = *(const s16x8*)&qp_s[32 * wave + tm * 16 + lr][ks * 32 + quad * 8];
            #pragma unroll
            for (int tn = 0; tn < 4; ++tn)
                bv[tn] = *(const s16x8*)&vt_s[pb][tn * 16 + lr][ks * 32 + quad * 8];
            #pragma unroll
            for (int tm = 0; tm < 2; ++tm)
                #pragma unroll
                for (int tn = 0; tn < 4; ++tn)
                    oacc[tm][tn] = __builtin_amdgcn_mfma_f32_16x16x32_bf16(
                        ap[tm], bv[tn], oacc[tm][tn], 0, 0, 0);
        }
    }

    #pragma unroll
    for (int tm = 0; tm < 2; ++tm)
        #pragma unroll
        for (int rg = 0; rg < 4; ++rg) {
            int row = i0 + tm * 16 + quad * 4 + rg;
            float linv = 1.0f / l_r[tm][rg];
            float* dst = out + (((size_t)b * S_ + n * W_ + row) * H_ + h) * D_ + lr;
            #pragma unroll
            for (int tn = 0; tn < 4; ++tn)
                dst[tn * 16] = oacc[tm][tn][rg] * linv;
        }
}

extern "C" void kernel_launch(void* const* d_in, const int* in_sizes, int n_in,
                              void* d_out, int out_size, void* d_ws, size_t ws_size,
                              hipStream_t stream)
{
    const float* xs       = (const float*)d_in[0];
    const float* prev_k   = (const float*)d_in[1];
    const float* prev_v   = (const float*)d_in[2];
    const float* w_q      = (const float*)d_in[3];
    const float* w_k      = (const float*)d_in[4];
    const float* w_v      = (const float*)d_in[5];
    const float* rel_bias = (const float*)d_in[6];
    float* out = (float*)d_out;

    short* xsbf  = (short*)d_ws;                        // 8192*512
    short* wt    = xsbf + (size_t)8192 * 512;           // 1536*512
    short* qkvbf = wt + (size_t)1536 * 512;             // 3*8192*512
    short* pkbf  = qkvbf + (size_t)3 * 8192 * 512;      // 524288
    short* pvbf  = pkbf + (size_t)524288;               // 524288

    convert_kernel<<<2560, 256, 0, stream>>>(xs, prev_k, prev_v, xsbf, pkbf, pvbf);
    transpose_w_kernel<<<dim3(8, 24), 256, 0, stream>>>(w_q, w_k, w_v, wt);

    proj_kernel<<<dim3(64, 12), 256, 0, stream>>>(xsbf, wt, qkvbf, out);

    attn_kernel<<<512, 256, 0, stream>>>(qkvbf, pkbf, pvbf, rel_bias, out);
}

// Round 6
// 146.836 us; speedup vs baseline: 30.7317x; 1.0268x over previous
//
#include <hip/hip_runtime.h>
#include <hip/hip_bf16.h>
#include <math.h>

#define B_ 2
#define S_ 4096
#define E_ 512
#define H_ 8
#define D_ 64
#define W_ 512
#define NW_ 8

#define MASKV -1e30f
#define MINIT -1e4f

typedef float f32x4 __attribute__((ext_vector_type(4)));
typedef short s16x4 __attribute__((ext_vector_type(4)));
typedef short s16x8 __attribute__((ext_vector_type(8)));
typedef unsigned int u32;
typedef __attribute__((address_space(1))) const u32 as1_u32;
typedef __attribute__((address_space(3))) u32 as3_u32;

__device__ inline short f2bf(float f) {
    unsigned u = __builtin_bit_cast(unsigned, f);
    unsigned r = (u + 0x7FFFu + ((u >> 16) & 1u)) >> 16;
    return (short)r;
}
__device__ inline s16x8 pack8(f32x4 a, f32x4 b) {
    s16x8 r;
    r[0]=f2bf(a[0]); r[1]=f2bf(a[1]); r[2]=f2bf(a[2]); r[3]=f2bf(a[3]);
    r[4]=f2bf(b[0]); r[5]=f2bf(b[1]); r[6]=f2bf(b[2]); r[7]=f2bf(b[3]);
    return r;
}
__device__ __forceinline__ void gl_lds16(const void* g, void* l) {
    __builtin_amdgcn_global_load_lds((as1_u32*)(unsigned long long)g,
                                     (as3_u32*)(u32)(unsigned long long)l,
                                     16, 0, 0);
}

// ---------------------------------------------------------------------------
// Pre-pass: xs, prev_k, prev_v fp32 -> bf16
// ---------------------------------------------------------------------------
__global__ void convert_kernel(const float* __restrict__ xs, const float* __restrict__ pk,
                               const float* __restrict__ pv, short* __restrict__ xsbf,
                               short* __restrict__ pkbf, short* __restrict__ pvbf)
{
    size_t i8 = ((size_t)blockIdx.x * 256 + threadIdx.x) * 8;
    const float* src; short* dst; size_t off;
    if (i8 < 4194304)            { src = xs; dst = xsbf; off = i8; }
    else if (i8 < 4194304+524288){ src = pk; dst = pkbf; off = i8 - 4194304; }
    else                         { src = pv; dst = pvbf; off = i8 - 4194304 - 524288; }
    f32x4 a = *(const f32x4*)(src + off);
    f32x4 b = *(const f32x4*)(src + off + 4);
    *(s16x8*)(dst + off) = pack8(a, b);
}

// ---------------------------------------------------------------------------
// Pre-pass: wt[z*512 + n][k] = w_z[k][n] * (z==0 ? 0.125 : 1), bf16
// ---------------------------------------------------------------------------
__global__ void transpose_w_kernel(const float* __restrict__ wq, const float* __restrict__ wk,
                                   const float* __restrict__ wv, short* __restrict__ wt)
{
    __shared__ float st[64][68];
    const int k0 = blockIdx.x * 64;
    const int nt = blockIdx.y;
    const int z  = nt >> 3;
    const int n0 = (nt & 7) * 64;
    const float* wz = (z == 0) ? wq : (z == 1) ? wk : wv;
    const float scale = (z == 0) ? 0.125f : 1.0f;
    const int tid = threadIdx.x;
    {
        int kk = tid >> 4, nn = (tid & 15) * 4;
        #pragma unroll
        for (int it = 0; it < 4; ++it) {
            f32x4 x = *(const f32x4*)(wz + (size_t)(k0 + kk + it * 16) * 512 + n0 + nn);
            *(f32x4*)&st[kk + it * 16][nn] = x;
        }
    }
    __syncthreads();
    {
        int nn2 = tid >> 2, kseg = (tid & 3) * 16;
        s16x8 o0, o1;
        #pragma unroll
        for (int j = 0; j < 8; ++j) o0[j] = f2bf(st[kseg + j][nn2] * scale);
        #pragma unroll
        for (int j = 0; j < 8; ++j) o1[j] = f2bf(st[kseg + 8 + j][nn2] * scale);
        short* dst = wt + (size_t)(z * 512 + n0 + nn2) * 512 + k0 + kseg;
        *(s16x8*)(dst) = o0;
        *(s16x8*)(dst + 8) = o1;
    }
}

// ---------------------------------------------------------------------------
// Fused QKV projection, global_load_lds staging + XOR-granule swizzle.
// 128(m) x 128(n) tiles, BK=64. Epilogue also writes next_k/next_v (fp32).
// ---------------------------------------------------------------------------
__global__ __launch_bounds__(256, 4)
void proj_kernel(const short* __restrict__ xsbf, const short* __restrict__ wt,
                 short* __restrict__ qkvbf, float* __restrict__ out)
{
    __shared__ short Xs[128][64];
    __shared__ short Ws[128][64];

    const int tid = threadIdx.x;
    const int m0  = blockIdx.x * 128;
    const int n0  = blockIdx.y * 128;
    const int z   = n0 >> 9;
    const int ln0 = n0 & 511;
    const int wave = tid >> 6, lane = tid & 63;
    const int wq = (wave & 1) * 64;
    const int wx = (wave >> 1) * 64;
    const int lr = lane & 15, quad = lane >> 4;

    f32x4 acc[4][4] = {};

    const int r8  = lane >> 3;
    const int gr  = lane & 7;

    for (int k0 = 0; k0 < 512; k0 += 64) {
        #pragma unroll
        for (int i = 0; i < 4; ++i) {
            int row = 32 * wave + 8 * i + r8;
            int gs  = gr ^ (row & 7);
            gl_lds16(xsbf + (size_t)(m0 + row) * 512 + k0 + gs * 8, &Xs[32 * wave + 8 * i][0]);
            gl_lds16(wt   + (size_t)(n0 + row) * 512 + k0 + gs * 8, &Ws[32 * wave + 8 * i][0]);
        }
        __syncthreads();
        #pragma unroll
        for (int ks = 0; ks < 2; ++ks) {
            s16x8 af[4], bf[4];
            #pragma unroll
            for (int ta = 0; ta < 4; ++ta) {
                int R = wq + ta * 16 + lr;
                af[ta] = *(const s16x8*)&Ws[R][(((ks * 4 + quad) ^ (R & 7)) * 8)];
            }
            #pragma unroll
            for (int tb = 0; tb < 4; ++tb) {
                int R = wx + tb * 16 + lr;
                bf[tb] = *(const s16x8*)&Xs[R][(((ks * 4 + quad) ^ (R & 7)) * 8)];
            }
            #pragma unroll
            for (int ta = 0; ta < 4; ++ta)
                #pragma unroll
                for (int tb = 0; tb < 4; ++tb)
                    acc[ta][tb] = __builtin_amdgcn_mfma_f32_16x16x32_bf16(
                        af[ta], bf[tb], acc[ta][tb], 0, 0, 0);
        }
        __syncthreads();
    }

    short* base = qkvbf + (size_t)z * ((size_t)8192 * 512);
    #pragma unroll
    for (int ta = 0; ta < 4; ++ta)
        #pragma unroll
        for (int tb = 0; tb < 4; ++tb) {
            int m  = m0 + wx + tb * 16 + lr;
            int ln = ln0 + wq + ta * 16 + quad * 4;
            s16x4 o;
            o[0] = f2bf(acc[ta][tb][0]); o[1] = f2bf(acc[ta][tb][1]);
            o[2] = f2bf(acc[ta][tb][2]); o[3] = f2bf(acc[ta][tb][3]);
            *(s16x4*)(base + (size_t)m * 512 + ln) = o;
            if (z != 0 && (m & 4095) >= 3584) {
                int bb = m >> 12, rr = (m & 4095) - 3584;
                float* dst = out + 4194304 + (size_t)(z - 1) * 524288
                           + ((size_t)(bb * 512 + rr)) * 512 + ln;
                *(f32x4*)dst = acc[ta][tb];
            }
        }
}

// ---------------------------------------------------------------------------
// MFMA flash attention: 512 threads = 8 waves x 16 q rows, 128-q tile.
// Double-buffered K/V + register prefetch; 16 waves/CU.
// ---------------------------------------------------------------------------
__global__ __launch_bounds__(512, 4)
void attn_kernel(const short* __restrict__ qkvbf, const short* __restrict__ pkbf,
                 const short* __restrict__ pvbf, const float* __restrict__ rel_bias,
                 float* __restrict__ out)
{
    __shared__ short p_s[128][72];       // per-wave P buffers (16 rows each)
    __shared__ short k_s[2][64][72];     // [buf][key][d]
    __shared__ short vt_s[2][64][72];    // [buf][d][key]
    __shared__ float bias_s[512];

    const short* qb = qkvbf;
    const short* kb = qkvbf + (size_t)8192 * 512;
    const short* vb = qkvbf + (size_t)2 * 8192 * 512;

    const int bid = blockIdx.x;
    const int qt = bid & 3;
    const int h  = (bid >> 2) & 7;
    const int n  = (bid >> 5) & 7;
    const int b  = bid >> 8;
    const int tid = threadIdx.x;
    const int wave = tid >> 6, lane = tid & 63;
    const int lr = lane & 15, quad = lane >> 4;
    const int q0 = qt * 128;
    const int i0 = q0 + 16 * wave;

    // T5 bias table: one entry per thread
    {
        int nd = tid;
        int bucket;
        if (nd < 16) bucket = nd;
        else {
            int vbk = 16 + (int)(log((double)nd * (1.0 / 16.0)) * (16.0 / log(8.0)));
            bucket = vbk < 31 ? vbk : 31;
        }
        bias_s[nd] = rel_bias[h * 32 + bucket];
    }

    // Q A-frags direct from global (one-time)
    s16x8 aq[2];
    {
        const short* src = qb + (size_t)(b * S_ + n * W_ + i0 + lr) * 512 + h * 64 + quad * 8;
        aq[0] = *(const s16x8*)(src);
        aq[1] = *(const s16x8*)(src + 32);
    }

    f32x4 oacc[4] = {};
    float m_r[4], l_r[4];
    #pragma unroll
    for (int rg = 0; rg < 4; ++rg) { m_r[rg] = MINIT; l_r[rg] = 0.f; }

    const int cmin = (16 * wave) >> 6;
    int cmax = (16 * wave + 528) >> 6; if (cmax > 9) cmax = 9;

    const int ksr = tid >> 3;             // K staging: key row 0..63
    const int ksd = (tid & 7) * 8;        // K staging: d segment (8 shorts)
    const int vkey = tid & 63;            // V staging: key = lane
    const int vd0 = (tid >> 6) * 8;       // V staging: 8 d-rows per wave

    // ---- prefetch chunk 0 ----
    s16x8 rk, rv;
    {
        int jj = q0 + ksr;
        int p  = n * W_ + jj - W_;
        const short* ks = (p >= 0) ? kb + (size_t)(b * S_ + p) * 512 + h * 64 + ksd
                                   : pkbf + ((size_t)(b * W_ + jj) * H_ + h) * D_ + ksd;
        rk = *(const s16x8*)ks;
        int jv = q0 + vkey;
        int pv = n * W_ + jv - W_;
        const short* vs = (pv >= 0) ? vb + (size_t)(b * S_ + pv) * 512 + h * 64 + vd0
                                    : pvbf + ((size_t)(b * W_ + jv) * H_ + h) * D_ + vd0;
        rv = *(const s16x8*)vs;
    }

    for (int c = 0; c < 10; ++c) {
        const int pb = c & 1;
        *(s16x8*)&k_s[pb][ksr][ksd] = rk;
        #pragma unroll
        for (int m = 0; m < 8; ++m) vt_s[pb][vd0 + m][vkey] = rv[m];

        // prefetch next chunk
        {
            int cn = (c < 9) ? c + 1 : 9;
            int jj = q0 + 64 * cn + ksr;
            int p  = n * W_ + jj - W_;
            const short* ks = (p >= 0) ? kb + (size_t)(b * S_ + p) * 512 + h * 64 + ksd
                                       : pkbf + ((size_t)(b * W_ + jj) * H_ + h) * D_ + ksd;
            rk = *(const s16x8*)ks;
            int jv = q0 + 64 * cn + vkey;
            int pv = n * W_ + jv - W_;
            const short* vs = (pv >= 0) ? vb + (size_t)(b * S_ + pv) * 512 + h * 64 + vd0
                                        : pvbf + ((size_t)(b * W_ + jv) * H_ + h) * D_ + vd0;
            rv = *(const s16x8*)vs;
        }

        __syncthreads();
        if (c < cmin || c > cmax) continue;

        // ---- S = Q K^T (16 x 64 per wave) ----
        f32x4 sacc[4] = {};
        #pragma unroll
        for (int ks = 0; ks < 2; ++ks) {
            s16x8 bk[4];
            #pragma unroll
            for (int tn = 0; tn < 4; ++tn)
                bk[tn] = *(const s16x8*)&k_s[pb][tn * 16 + lr][ks * 32 + quad * 8];
            #pragma unroll
            for (int tn = 0; tn < 4; ++tn)
                sacc[tn] = __builtin_amdgcn_mfma_f32_16x16x32_bf16(
                    aq[ks], bk[tn], sacc[tn], 0, 0, 0);
        }

        // ---- bias + mask (C-layout: col=lr is key, row=quad*4+rg is q) ----
        const int jc = q0 + 64 * c + lr;
        #pragma unroll
        for (int tn = 0; tn < 4; ++tn) {
            int j = jc + tn * 16;
            #pragma unroll
            for (int rg = 0; rg < 4; ++rg) {
                int i = i0 + quad * 4 + rg;
                unsigned dm1 = (unsigned)(j - i - 1);
                int nd = (i + 512 - j) & 511;
                float sv = sacc[tn][rg] + bias_s[nd];
                sacc[tn][rg] = (dm1 < 512u) ? sv : MASKV;
            }
        }

        // ---- online softmax (per rg row, butterfly over 16 lanes) ----
        float rmax[4];
        #pragma unroll
        for (int rg = 0; rg < 4; ++rg)
            rmax[rg] = fmaxf(fmaxf(sacc[0][rg], sacc[1][rg]),
                             fmaxf(sacc[2][rg], sacc[3][rg]));
        #pragma unroll
        for (int off = 1; off < 16; off <<= 1)
            #pragma unroll
            for (int rg = 0; rg < 4; ++rg)
                rmax[rg] = fmaxf(rmax[rg], __shfl_xor(rmax[rg], off));

        float al[4], rs[4];
        #pragma unroll
        for (int rg = 0; rg < 4; ++rg) {
            float mo = m_r[rg];
            float mn = fmaxf(mo, rmax[rg]);
            al[rg] = __expf(mo - mn);
            m_r[rg] = mn;
            rs[rg] = 0.f;
        }

        #pragma unroll
        for (int tn = 0; tn < 4; ++tn)
            #pragma unroll
            for (int rg = 0; rg < 4; ++rg) {
                float p = __expf(sacc[tn][rg] - m_r[rg]);
                rs[rg] += p;
                p_s[16 * wave + quad * 4 + rg][tn * 16 + lr] = f2bf(p);
            }

        #pragma unroll
        for (int off = 1; off < 16; off <<= 1)
            #pragma unroll
            for (int rg = 0; rg < 4; ++rg)
                rs[rg] += __shfl_xor(rs[rg], off);

        #pragma unroll
        for (int rg = 0; rg < 4; ++rg)
            l_r[rg] = l_r[rg] * al[rg] + rs[rg];

        #pragma unroll
        for (int tn = 0; tn < 4; ++tn)
            #pragma unroll
            for (int rg = 0; rg < 4; ++rg)
                oacc[tn][rg] *= al[rg];

        asm volatile("s_waitcnt lgkmcnt(0)" ::: "memory");

        // ---- O += P V ----
        #pragma unroll
        for (int ks = 0; ks < 2; ++ks) {
            s16x8 ap = *(const s16x8*)&p_s[16 * wave + lr][ks * 32 + quad * 8];
            s16x8 bv[4];
            #pragma unroll
            for (int tn = 0; tn < 4; ++tn)
                bv[tn] = *(const s16x8*)&vt_s[pb][tn * 16 + lr][ks * 32 + quad * 8];
            #pragma unroll
            for (int tn = 0; tn < 4; ++tn)
                oacc[tn] = __builtin_amdgcn_mfma_f32_16x16x32_bf16(
                    ap, bv[tn], oacc[tn], 0, 0, 0);
        }
    }

    #pragma unroll
    for (int rg = 0; rg < 4; ++rg) {
        int row = i0 + quad * 4 + rg;
        float linv = 1.0f / l_r[rg];
        float* dst = out + (((size_t)b * S_ + n * W_ + row) * H_ + h) * D_ + lr;
        #pragma unroll
        for (int tn = 0; tn < 4; ++tn)
            dst[tn * 16] = oacc[tn][rg] * linv;
    }
}

extern "C" void kernel_launch(void* const* d_in, const int* in_sizes, int n_in,
                              void* d_out, int out_size, void* d_ws, size_t ws_size,
                              hipStream_t stream)
{
    const float* xs       = (const float*)d_in[0];
    const float* prev_k   = (const float*)d_in[1];
    const float* prev_v   = (const float*)d_in[2];
    const float* w_q      = (const float*)d_in[3];
    const float* w_k      = (const float*)d_in[4];
    const float* w_v      = (const float*)d_in[5];
    const float* rel_bias = (const float*)d_in[6];
    float* out = (float*)d_out;

    short* xsbf  = (short*)d_ws;
    short* wt    = xsbf + (size_t)8192 * 512;
    short* qkvbf = wt + (size_t)1536 * 512;
    short* pkbf  = qkvbf + (size_t)3 * 8192 * 512;
    short* pvbf  = pkbf + (size_t)524288;

    convert_kernel<<<2560, 256, 0, stream>>>(xs, prev_k, prev_v, xsbf, pkbf, pvbf);
    transpose_w_kernel<<<dim3(8, 24), 256, 0, stream>>>(w_q, w_k, w_v, wt);

    proj_kernel<<<dim3(64, 12), 256, 0, stream>>>(xsbf, wt, qkvbf, out);

    attn_kernel<<<512, 512, 0, stream>>>(qkvbf, pkbf, pvbf, rel_bias, out);
}

// Round 9
// 135.710 us; speedup vs baseline: 33.2512x; 1.0820x over previous
//
#include <hip/hip_runtime.h>
#include <hip/hip_bf16.h>
#include <math.h>

#define B_ 2
#define S_ 4096
#define H_ 8
#define D_ 64
#define W_ 512

#define MASKV -1e30f

typedef float f32x4 __attribute__((ext_vector_type(4)));
typedef short s16x4 __attribute__((ext_vector_type(4)));
typedef short s16x8 __attribute__((ext_vector_type(8)));
typedef unsigned int u32;
typedef __attribute__((address_space(1))) const u32 as1_u32;
typedef __attribute__((address_space(3))) u32 as3_u32;

__device__ inline short f2bf(float f) {
    unsigned u = __builtin_bit_cast(unsigned, f);
    unsigned r = (u + 0x7FFFu + ((u >> 16) & 1u)) >> 16;
    return (short)r;
}
__device__ inline s16x8 pack8(f32x4 a, f32x4 b) {
    s16x8 r;
    r[0]=f2bf(a[0]); r[1]=f2bf(a[1]); r[2]=f2bf(a[2]); r[3]=f2bf(a[3]);
    r[4]=f2bf(b[0]); r[5]=f2bf(b[1]); r[6]=f2bf(b[2]); r[7]=f2bf(b[3]);
    return r;
}
__device__ __forceinline__ void gl_lds16(const void* g, void* l) {
    __builtin_amdgcn_global_load_lds((as1_u32*)(unsigned long long)g,
                                     (as3_u32*)(u32)(unsigned long long)l,
                                     16, 0, 0);
}
// drain ALL outstanding async global->LDS writes of this wave; must precede
// s_barrier so other waves see our staged rows after barrier release.
__device__ __forceinline__ void drain_vmem() {
    asm volatile("s_waitcnt vmcnt(0)" ::: "memory");
}

// ---------------------------------------------------------------------------
// Pre-pass: xs + prev_k fp32 -> bf16 (flat)
// ---------------------------------------------------------------------------
__global__ void convert_kernel(const float* __restrict__ xs, const float* __restrict__ pk,
                               short* __restrict__ xsbf, short* __restrict__ pkbf)
{
    size_t i8 = ((size_t)blockIdx.x * 256 + threadIdx.x) * 8;
    const float* src; short* dst; size_t off;
    if (i8 < 4194304) { src = xs; dst = xsbf; off = i8; }
    else              { src = pk; dst = pkbf; off = i8 - 4194304; }
    f32x4 a = *(const f32x4*)(src + off);
    f32x4 b = *(const f32x4*)(src + off + 4);
    *(s16x8*)(dst + off) = pack8(a, b);
}

// ---------------------------------------------------------------------------
// Pre-pass: prev_v (fp32 [b][jj][h][d]) -> vbt bf16 [h*64+d][b*4608 + jj]
// ---------------------------------------------------------------------------
__global__ void prev_v_t_kernel(const float* __restrict__ pv, short* __restrict__ vbt)
{
    __shared__ short st[64][72];
    const int bidx = blockIdx.x;
    const int jt = bidx & 7, h = (bidx >> 3) & 7, b = bidx >> 6;
    const int jj0 = jt * 64;
    const int tid = threadIdx.x;
    {
        int kk = tid >> 2, d0 = (tid & 3) * 16;
        const float* src = pv + (((size_t)(b * 512 + jj0 + kk)) * 8 + h) * 64 + d0;
        f32x4 x0 = *(const f32x4*)(src);
        f32x4 x1 = *(const f32x4*)(src + 4);
        f32x4 x2 = *(const f32x4*)(src + 8);
        f32x4 x3 = *(const f32x4*)(src + 12);
        *(s16x8*)&st[kk][d0]     = pack8(x0, x1);
        *(s16x8*)&st[kk][d0 + 8] = pack8(x2, x3);
    }
    __syncthreads();
    {
        int dd = tid >> 2, k0 = (tid & 3) * 16;
        s16x8 o0, o1;
        #pragma unroll
        for (int t = 0; t < 8; ++t) { o0[t] = st[k0 + t][dd]; o1[t] = st[k0 + 8 + t][dd]; }
        short* dst = vbt + (size_t)(h * 64 + dd) * 9216 + b * 4608 + jj0 + k0;
        *(s16x8*)dst = o0;
        *(s16x8*)(dst + 8) = o1;
    }
}

// ---------------------------------------------------------------------------
// Pre-pass: wt[z*512 + n][k] = w_z[k][n] * (z==0 ? 0.125 : 1), bf16
// ---------------------------------------------------------------------------
__global__ void transpose_w_kernel(const float* __restrict__ wq, const float* __restrict__ wk,
                                   const float* __restrict__ wv, short* __restrict__ wt)
{
    __shared__ float st[64][68];
    const int k0 = blockIdx.x * 64;
    const int nt = blockIdx.y;
    const int z  = nt >> 3;
    const int n0 = (nt & 7) * 64;
    const float* wz = (z == 0) ? wq : (z == 1) ? wk : wv;
    const float scale = (z == 0) ? 0.125f : 1.0f;
    const int tid = threadIdx.x;
    {
        int kk = tid >> 4, nn = (tid & 15) * 4;
        #pragma unroll
        for (int it = 0; it < 4; ++it) {
            f32x4 x = *(const f32x4*)(wz + (size_t)(k0 + kk + it * 16) * 512 + n0 + nn);
            *(f32x4*)&st[kk + it * 16][nn] = x;
        }
    }
    __syncthreads();
    {
        int nn2 = tid >> 2, kseg = (tid & 3) * 16;
        s16x8 o0, o1;
        #pragma unroll
        for (int j = 0; j < 8; ++j) o0[j] = f2bf(st[kseg + j][nn2] * scale);
        #pragma unroll
        for (int j = 0; j < 8; ++j) o1[j] = f2bf(st[kseg + 8 + j][nn2] * scale);
        short* dst = wt + (size_t)(z * 512 + n0 + nn2) * 512 + k0 + kseg;
        *(s16x8*)(dst) = o0;
        *(s16x8*)(dst + 8) = o1;
    }
}

// ---------------------------------------------------------------------------
// Fused QKV projection. z=0/1 -> row-major bf16 q/k; z=2 -> transposed vbt.
// Epilogue also writes next_k/next_v (fp32).
// ---------------------------------------------------------------------------
__global__ __launch_bounds__(256, 4)
void proj_kernel(const short* __restrict__ xsbf, const short* __restrict__ wt,
                 short* __restrict__ qkbf, short* __restrict__ vbt,
                 float* __restrict__ out)
{
    __shared__ short Xs[128][64];
    __shared__ short Ws[128][64];

    const int tid = threadIdx.x;
    const int m0  = blockIdx.x * 128;
    const int n0  = blockIdx.y * 128;
    const int z   = n0 >> 9;
    const int ln0 = n0 & 511;
    const int wave = tid >> 6, lane = tid & 63;
    const int wq = (wave & 1) * 64;
    const int wx = (wave >> 1) * 64;
    const int lr = lane & 15, quad = lane >> 4;

    f32x4 acc[4][4] = {};

    const int r8  = lane >> 3;
    const int gr  = lane & 7;

    for (int k0 = 0; k0 < 512; k0 += 64) {
        #pragma unroll
        for (int i = 0; i < 4; ++i) {
            int row = 32 * wave + 8 * i + r8;
            int gs  = gr ^ (row & 7);
            gl_lds16(xsbf + (size_t)(m0 + row) * 512 + k0 + gs * 8, &Xs[32 * wave + 8 * i][0]);
            gl_lds16(wt   + (size_t)(n0 + row) * 512 + k0 + gs * 8, &Ws[32 * wave + 8 * i][0]);
        }
        drain_vmem();
        __syncthreads();
        #pragma unroll
        for (int ks = 0; ks < 2; ++ks) {
            s16x8 af[4], bf[4];
            #pragma unroll
            for (int ta = 0; ta < 4; ++ta) {
                int R = wq + ta * 16 + lr;
                af[ta] = *(const s16x8*)&Ws[R][(((ks * 4 + quad) ^ (R & 7)) * 8)];
            }
            #pragma unroll
            for (int tb = 0; tb < 4; ++tb) {
                int R = wx + tb * 16 + lr;
                bf[tb] = *(const s16x8*)&Xs[R][(((ks * 4 + quad) ^ (R & 7)) * 8)];
            }
            #pragma unroll
            for (int ta = 0; ta < 4; ++ta)
                #pragma unroll
                for (int tb = 0; tb < 4; ++tb)
                    acc[ta][tb] = __builtin_amdgcn_mfma_f32_16x16x32_bf16(
                        af[ta], bf[tb], acc[ta][tb], 0, 0, 0);
        }
        __syncthreads();
    }

    #pragma unroll
    for (int ta = 0; ta < 4; ++ta)
        #pragma unroll
        for (int tb = 0; tb < 4; ++tb) {
            int m  = m0 + wx + tb * 16 + lr;
            int ln = ln0 + wq + ta * 16 + quad * 4;
            int bb = m >> 12, seq = m & 4095;
            if (z < 2) {
                short* base = qkbf + (size_t)z * ((size_t)8192 * 512);
                s16x4 o;
                o[0] = f2bf(acc[ta][tb][0]); o[1] = f2bf(acc[ta][tb][1]);
                o[2] = f2bf(acc[ta][tb][2]); o[3] = f2bf(acc[ta][tb][3]);
                *(s16x4*)(base + (size_t)m * 512 + ln) = o;
                if (z == 1 && seq >= 3584) {
                    float* dst = out + 4194304 + ((size_t)(bb * 512 + seq - 3584)) * 512 + ln;
                    *(f32x4*)dst = acc[ta][tb];
                }
            } else {
                size_t col = (size_t)bb * 4608 + 512 + seq;
                #pragma unroll
                for (int g = 0; g < 4; ++g)
                    vbt[(size_t)(ln + g) * 9216 + col] = f2bf(acc[ta][tb][g]);
                if (seq >= 3584) {
                    float* dst = out + 4194304 + 524288 + ((size_t)(bb * 512 + seq - 3584)) * 512 + ln;
                    *(f32x4*)dst = acc[ta][tb];
                }
            }
        }
}

// ---------------------------------------------------------------------------
// MFMA flash attention, S^T formulation + fixed-max softmax + async staging.
// Block = (b, window n, head h, 128 q rows); 512 thr = 8 waves x 16 q rows.
// ---------------------------------------------------------------------------
__global__ __launch_bounds__(512, 4)
void attn_kernel(const short* __restrict__ qkbf, const short* __restrict__ vbt,
                 const short* __restrict__ pkbf, const float* __restrict__ rel_bias,
                 float* __restrict__ out)
{
    __shared__ short k_s[2][64][64];     // [buf][key][d], XOR-swizzled granules
    __shared__ short vt_s[2][64][64];    // [buf][d][key], XOR-swizzled granules
    __shared__ short p_s[128][64];       // per-wave P rows, XOR-swizzled
    __shared__ float bias_s[512];

    const short* qb = qkbf;
    const short* kb = qkbf + (size_t)8192 * 512;

    const int bid = blockIdx.x;
    const int qt = bid & 3;
    const int h  = (bid >> 2) & 7;
    const int n  = (bid >> 5) & 7;
    const int b  = bid >> 8;
    const int tid = threadIdx.x;
    const int wave = tid >> 6, lane = tid & 63;
    const int lr = lane & 15, quad = lane >> 4;
    const int q0 = qt * 128;
    const int i0 = q0 + 16 * wave;

    // T5 bias table (512 entries, one per thread)
    {
        int nd = tid;
        int bucket;
        if (nd < 16) bucket = nd;
        else {
            int vbk = 16 + (int)(log((double)nd * (1.0 / 16.0)) * (16.0 / log(8.0)));
            bucket = vbk < 31 ? vbk : 31;
        }
        bias_s[nd] = rel_bias[h * 32 + bucket];
    }
    const float bias31 = rel_bias[h * 32 + 31];

    // Q B-frag direct from global
    s16x8 aq[2];
    {
        const short* src = qb + (size_t)(b * S_ + n * W_ + i0 + lr) * 512 + h * 64 + quad * 8;
        aq[0] = *(const s16x8*)(src);
        aq[1] = *(const s16x8*)(src + 32);
    }

    f32x4 oacc[4] = {};
    float lsum = 0.f;

    const int cmin = (16 * wave) >> 6;
    const int cmax = (16 * wave + 527) >> 6;

    const int r8 = lane >> 3, gr = lane & 7;

    // async staging: wave w stages rows 8w..8w+7 of K chunk and of V^T chunk
    // keys for chunk c are jj in [q0 + 64c, q0 + 64c + 64)  (window coords)
    auto issueKV = [&](int c, int pb) {
        int jj = q0 + 64 * c + 8 * wave + r8;          // key in [q0, q0+640)
        int p  = n * W_ + jj - W_;
        int gs = gr ^ r8;
        const short* ksrc = (p >= 0)
            ? kb   + ((size_t)(b * S_ + p)) * 512 + h * 64 + gs * 8
            : pkbf + (((size_t)(b * W_ + jj)) * 8 + h) * 64 + gs * 8;
        gl_lds16(ksrc, &k_s[pb][8 * wave][0]);
        int drow = 8 * wave + r8;
        const short* vsrc = vbt + (size_t)(h * 64 + drow) * 9216
                          + b * 4608 + n * W_ + q0 + 64 * c + gs * 8;
        gl_lds16(vsrc, &vt_s[pb][8 * wave][0]);
    };

    issueKV(0, 0);

    for (int c = 0; c < 10; ++c) {
        const int pb = c & 1;
        drain_vmem();                    // our async writes land BEFORE barrier
        __syncthreads();                 // now all waves' chunk-c rows are valid
        if (c < 9) issueKV(c + 1, pb ^ 1);   // overlaps compute below
        if (c < cmin || c > cmax) continue;

        // ---- S^T = K * Q^T : D[key][q], col=lane&15=q, row=quad*4+rg=key ----
        f32x4 sacc[4] = {};
        #pragma unroll
        for (int ks = 0; ks < 2; ++ks) {
            s16x8 bk[4];
            #pragma unroll
            for (int tn = 0; tn < 4; ++tn)
                bk[tn] = *(const s16x8*)&k_s[pb][tn * 16 + lr][(((4 * ks + quad) ^ (lr & 7)) * 8)];
            #pragma unroll
            for (int tn = 0; tn < 4; ++tn)
                sacc[tn] = __builtin_amdgcn_mfma_f32_16x16x32_bf16(
                    bk[tn], aq[ks], sacc[tn], 0, 0, 0);
        }

        // ---- bias + mask + exp (no running max needed) ----
        const int ib = i0 + lr;          // this lane's q row (window coords)
        const int jb = q0 + 64 * c;
        if (64 * c - 16 * wave <= 336) {
            // all valid pairs have nd >= 113 -> bucket 31 (constant bias)
            #pragma unroll
            for (int tn = 0; tn < 4; ++tn) {
                s16x4 pp;
                #pragma unroll
                for (int rg = 0; rg < 4; ++rg) {
                    int j = jb + tn * 16 + quad * 4 + rg;
                    unsigned dm1 = (unsigned)(j - ib - 1);
                    float sv = (dm1 < 512u) ? (sacc[tn][rg] + bias31) : MASKV;
                    float p = __expf(sv);
                    lsum += p;
                    pp[rg] = f2bf(p);
                }
                int gp = (2 * tn + (quad >> 1)) ^ (lr & 7);
                *(s16x4*)&p_s[16 * wave + lr][gp * 8 + (quad & 1) * 4] = pp;
            }
        } else {
            #pragma unroll
            for (int tn = 0; tn < 4; ++tn) {
                s16x4 pp;
                #pragma unroll
                for (int rg = 0; rg < 4; ++rg) {
                    int j = jb + tn * 16 + quad * 4 + rg;
                    unsigned dm1 = (unsigned)(j - ib - 1);
                    float bias = bias_s[(ib + 512 - j) & 511];
                    float sv = (dm1 < 512u) ? (sacc[tn][rg] + bias) : MASKV;
                    float p = __expf(sv);
                    lsum += p;
                    pp[rg] = f2bf(p);
                }
                int gp = (2 * tn + (quad >> 1)) ^ (lr & 7);
                *(s16x4*)&p_s[16 * wave + lr][gp * 8 + (quad & 1) * 4] = pp;
            }
        }

        asm volatile("s_waitcnt lgkmcnt(0)" ::: "memory");

        // ---- O += P V : A=P (q x keys), B=V (keys x d) ----
        #pragma unroll
        for (int ks = 0; ks < 2; ++ks) {
            int gpa = (4 * ks + quad) ^ (lr & 7);
            s16x8 ap = *(const s16x8*)&p_s[16 * wave + lr][gpa * 8];
            s16x8 bv[4];
            #pragma unroll
            for (int tn = 0; tn < 4; ++tn)
                bv[tn] = *(const s16x8*)&vt_s[pb][tn * 16 + lr][(((4 * ks + quad) ^ (lr & 7)) * 8)];
            #pragma unroll
            for (int tn = 0; tn < 4; ++tn)
                oacc[tn] = __builtin_amdgcn_mfma_f32_16x16x32_bf16(
                    ap, bv[tn], oacc[tn], 0, 0, 0);
        }
    }

    // ---- final l reduction over quads; redistribute; store ----
    lsum += __shfl_xor(lsum, 16);
    lsum += __shfl_xor(lsum, 32);
    float linv[4];
    #pragma unroll
    for (int rg = 0; rg < 4; ++rg)
        linv[rg] = 1.0f / __shfl(lsum, quad * 4 + rg);

    #pragma unroll
    for (int rg = 0; rg < 4; ++rg) {
        int row = i0 + quad * 4 + rg;
        float* dst = out + (((size_t)b * S_ + n * W_ + row) * H_ + h) * D_ + lr;
        #pragma unroll
        for (int tn = 0; tn < 4; ++tn)
            dst[tn * 16] = oacc[tn][rg] * linv[rg];
    }
}

extern "C" void kernel_launch(void* const* d_in, const int* in_sizes, int n_in,
                              void* d_out, int out_size, void* d_ws, size_t ws_size,
                              hipStream_t stream)
{
    const float* xs       = (const float*)d_in[0];
    const float* prev_k   = (const float*)d_in[1];
    const float* prev_v   = (const float*)d_in[2];
    const float* w_q      = (const float*)d_in[3];
    const float* w_k      = (const float*)d_in[4];
    const float* w_v      = (const float*)d_in[5];
    const float* rel_bias = (const float*)d_in[6];
    float* out = (float*)d_out;

    short* xsbf = (short*)d_ws;                         // 4,194,304
    short* wt   = xsbf + (size_t)4194304;               //   786,432
    short* qkbf = wt   + (size_t)786432;                // 8,388,608 (q then k)
    short* pkbf = qkbf + (size_t)8388608;               //   524,288
    short* vbt  = pkbf + (size_t)524288;                // 512 x 9216

    convert_kernel<<<2304, 256, 0, stream>>>(xs, prev_k, xsbf, pkbf);
    prev_v_t_kernel<<<128, 256, 0, stream>>>(prev_v, vbt);
    transpose_w_kernel<<<dim3(8, 24), 256, 0, stream>>>(w_q, w_k, w_v, wt);

    proj_kernel<<<dim3(64, 12), 256, 0, stream>>>(xsbf, wt, qkbf, vbt, out);

    attn_kernel<<<512, 512, 0, stream>>>(qkbf, vbt, pkbf, rel_bias, out);
}

// Round 10
// 127.228 us; speedup vs baseline: 35.4680x; 1.0667x over previous
//
#include <hip/hip_runtime.h>
#include <hip/hip_bf16.h>
#include <math.h>

#define B_ 2
#define S_ 4096
#define H_ 8
#define D_ 64
#define W_ 512

#define MASKV -1e30f

typedef float f32x4 __attribute__((ext_vector_type(4)));
typedef short s16x4 __attribute__((ext_vector_type(4)));
typedef short s16x8 __attribute__((ext_vector_type(8)));
typedef unsigned int u32;
typedef __attribute__((address_space(1))) const u32 as1_u32;
typedef __attribute__((address_space(3))) u32 as3_u32;

__device__ inline short f2bf(float f) {
    unsigned u = __builtin_bit_cast(unsigned, f);
    unsigned r = (u + 0x7FFFu + ((u >> 16) & 1u)) >> 16;
    return (short)r;
}
__device__ inline s16x8 pack8(f32x4 a, f32x4 b) {
    s16x8 r;
    r[0]=f2bf(a[0]); r[1]=f2bf(a[1]); r[2]=f2bf(a[2]); r[3]=f2bf(a[3]);
    r[4]=f2bf(b[0]); r[5]=f2bf(b[1]); r[6]=f2bf(b[2]); r[7]=f2bf(b[3]);
    return r;
}
__device__ __forceinline__ void gl_lds16(const void* g, void* l) {
    __builtin_amdgcn_global_load_lds((as1_u32*)(unsigned long long)g,
                                     (as3_u32*)(u32)(unsigned long long)l,
                                     16, 0, 0);
}
// drain ALL outstanding async global->LDS writes of this wave; must precede
// s_barrier so other waves see our staged rows after barrier release.
__device__ __forceinline__ void drain_vmem() {
    asm volatile("s_waitcnt vmcnt(0)" ::: "memory");
}

// ---------------------------------------------------------------------------
// Fused pre-pass (one launch):
//   blocks [0,2304):    xs + prev_k fp32 -> bf16 flat
//   blocks [2304,2432): prev_v -> vbt bf16 [h*64+d][b*4608 + jj]
//   blocks [2432,2624): wt[z*512+n][k] = w_z[k][n] * scale_z, bf16
// ---------------------------------------------------------------------------
__global__ __launch_bounds__(256, 4)
void prep_kernel(const float* __restrict__ xs, const float* __restrict__ pk,
                 const float* __restrict__ pv, const float* __restrict__ wq,
                 const float* __restrict__ wk, const float* __restrict__ wv,
                 short* __restrict__ xsbf, short* __restrict__ pkbf,
                 short* __restrict__ vbt, short* __restrict__ wt)
{
    __shared__ char smem[17408];
    const int bid = blockIdx.x;
    const int tid = threadIdx.x;

    if (bid < 2304) {
        // ---- convert xs + prev_k ----
        size_t i8 = ((size_t)bid * 256 + tid) * 8;
        const float* src; short* dst; size_t off;
        if (i8 < 4194304) { src = xs; dst = xsbf; off = i8; }
        else              { src = pk; dst = pkbf; off = i8 - 4194304; }
        f32x4 a = *(const f32x4*)(src + off);
        f32x4 b = *(const f32x4*)(src + off + 4);
        *(s16x8*)(dst + off) = pack8(a, b);
    } else if (bid < 2432) {
        // ---- prev_v transpose ----
        short (*st)[72] = (short(*)[72])smem;
        const int b2 = bid - 2304;
        const int jt = b2 & 7, h = (b2 >> 3) & 7, b = b2 >> 6;
        const int jj0 = jt * 64;
        {
            int kk = tid >> 2, d0 = (tid & 3) * 16;
            const float* src = pv + (((size_t)(b * 512 + jj0 + kk)) * 8 + h) * 64 + d0;
            f32x4 x0 = *(const f32x4*)(src);
            f32x4 x1 = *(const f32x4*)(src + 4);
            f32x4 x2 = *(const f32x4*)(src + 8);
            f32x4 x3 = *(const f32x4*)(src + 12);
            *(s16x8*)&st[kk][d0]     = pack8(x0, x1);
            *(s16x8*)&st[kk][d0 + 8] = pack8(x2, x3);
        }
        __syncthreads();
        {
            int dd = tid >> 2, k0 = (tid & 3) * 16;
            s16x8 o0, o1;
            #pragma unroll
            for (int t = 0; t < 8; ++t) { o0[t] = st[k0 + t][dd]; o1[t] = st[k0 + 8 + t][dd]; }
            short* dst = vbt + (size_t)(h * 64 + dd) * 9216 + b * 4608 + jj0 + k0;
            *(s16x8*)dst = o0;
            *(s16x8*)(dst + 8) = o1;
        }
    } else {
        // ---- weight transpose ----
        float (*st)[68] = (float(*)[68])smem;
        const int t2 = bid - 2432;
        const int k0 = (t2 & 7) * 64;
        const int nt = t2 >> 3;
        const int z  = nt >> 3;
        const int n0 = (nt & 7) * 64;
        const float* wz = (z == 0) ? wq : (z == 1) ? wk : wv;
        const float scale = (z == 0) ? 0.125f : 1.0f;
        {
            int kk = tid >> 4, nn = (tid & 15) * 4;
            #pragma unroll
            for (int it = 0; it < 4; ++it) {
                f32x4 x = *(const f32x4*)(wz + (size_t)(k0 + kk + it * 16) * 512 + n0 + nn);
                *(f32x4*)&st[kk + it * 16][nn] = x;
            }
        }
        __syncthreads();
        {
            int nn2 = tid >> 2, kseg = (tid & 3) * 16;
            s16x8 o0, o1;
            #pragma unroll
            for (int j = 0; j < 8; ++j) o0[j] = f2bf(st[kseg + j][nn2] * scale);
            #pragma unroll
            for (int j = 0; j < 8; ++j) o1[j] = f2bf(st[kseg + 8 + j][nn2] * scale);
            short* dst = wt + (size_t)(z * 512 + n0 + nn2) * 512 + k0 + kseg;
            *(s16x8*)(dst) = o0;
            *(s16x8*)(dst + 8) = o1;
        }
    }
}

// ---------------------------------------------------------------------------
// Fused QKV projection. z=0/1 -> row-major bf16 q/k; z=2 -> transposed vbt.
// Epilogue also writes next_k/next_v (fp32).
// ---------------------------------------------------------------------------
__global__ __launch_bounds__(256, 4)
void proj_kernel(const short* __restrict__ xsbf, const short* __restrict__ wt,
                 short* __restrict__ qkbf, short* __restrict__ vbt,
                 float* __restrict__ out)
{
    __shared__ short Xs[128][64];
    __shared__ short Ws[128][64];

    const int tid = threadIdx.x;
    const int m0  = blockIdx.x * 128;
    const int n0  = blockIdx.y * 128;
    const int z   = n0 >> 9;
    const int ln0 = n0 & 511;
    const int wave = tid >> 6, lane = tid & 63;
    const int wq = (wave & 1) * 64;
    const int wx = (wave >> 1) * 64;
    const int lr = lane & 15, quad = lane >> 4;

    f32x4 acc[4][4] = {};

    const int r8  = lane >> 3;
    const int gr  = lane & 7;

    for (int k0 = 0; k0 < 512; k0 += 64) {
        #pragma unroll
        for (int i = 0; i < 4; ++i) {
            int row = 32 * wave + 8 * i + r8;
            int gs  = gr ^ (row & 7);
            gl_lds16(xsbf + (size_t)(m0 + row) * 512 + k0 + gs * 8, &Xs[32 * wave + 8 * i][0]);
            gl_lds16(wt   + (size_t)(n0 + row) * 512 + k0 + gs * 8, &Ws[32 * wave + 8 * i][0]);
        }
        drain_vmem();
        __syncthreads();
        #pragma unroll
        for (int ks = 0; ks < 2; ++ks) {
            s16x8 af[4], bf[4];
            #pragma unroll
            for (int ta = 0; ta < 4; ++ta) {
                int R = wq + ta * 16 + lr;
                af[ta] = *(const s16x8*)&Ws[R][(((ks * 4 + quad) ^ (R & 7)) * 8)];
            }
            #pragma unroll
            for (int tb = 0; tb < 4; ++tb) {
                int R = wx + tb * 16 + lr;
                bf[tb] = *(const s16x8*)&Xs[R][(((ks * 4 + quad) ^ (R & 7)) * 8)];
            }
            #pragma unroll
            for (int ta = 0; ta < 4; ++ta)
                #pragma unroll
                for (int tb = 0; tb < 4; ++tb)
                    acc[ta][tb] = __builtin_amdgcn_mfma_f32_16x16x32_bf16(
                        af[ta], bf[tb], acc[ta][tb], 0, 0, 0);
        }
        __syncthreads();
    }

    #pragma unroll
    for (int ta = 0; ta < 4; ++ta)
        #pragma unroll
        for (int tb = 0; tb < 4; ++tb) {
            int m  = m0 + wx + tb * 16 + lr;
            int ln = ln0 + wq + ta * 16 + quad * 4;
            int bb = m >> 12, seq = m & 4095;
            if (z < 2) {
                short* base = qkbf + (size_t)z * ((size_t)8192 * 512);
                s16x4 o;
                o[0] = f2bf(acc[ta][tb][0]); o[1] = f2bf(acc[ta][tb][1]);
                o[2] = f2bf(acc[ta][tb][2]); o[3] = f2bf(acc[ta][tb][3]);
                *(s16x4*)(base + (size_t)m * 512 + ln) = o;
                if (z == 1 && seq >= 3584) {
                    float* dst = out + 4194304 + ((size_t)(bb * 512 + seq - 3584)) * 512 + ln;
                    *(f32x4*)dst = acc[ta][tb];
                }
            } else {
                size_t col = (size_t)bb * 4608 + 512 + seq;
                #pragma unroll
                for (int g = 0; g < 4; ++g)
                    vbt[(size_t)(ln + g) * 9216 + col] = f2bf(acc[ta][tb][g]);
                if (seq >= 3584) {
                    float* dst = out + 4194304 + 524288 + ((size_t)(bb * 512 + seq - 3584)) * 512 + ln;
                    *(f32x4*)dst = acc[ta][tb];
                }
            }
        }
}

// ---------------------------------------------------------------------------
// MFMA flash attention, S^T formulation + fixed-max softmax + async staging.
// Block = (b, window n, head h, 128 q rows); 512 thr = 8 waves x 16 q rows.
// ---------------------------------------------------------------------------
__global__ __launch_bounds__(512, 4)
void attn_kernel(const short* __restrict__ qkbf, const short* __restrict__ vbt,
                 const short* __restrict__ pkbf, const float* __restrict__ rel_bias,
                 float* __restrict__ out)
{
    __shared__ short k_s[2][64][64];     // [buf][key][d], XOR-swizzled granules
    __shared__ short vt_s[2][64][64];    // [buf][d][key], XOR-swizzled granules
    __shared__ short p_s[128][64];       // per-wave P rows, XOR-swizzled
    __shared__ float bias_s[512];

    const short* qb = qkbf;
    const short* kb = qkbf + (size_t)8192 * 512;

    const int bid = blockIdx.x;
    const int qt = bid & 3;
    const int h  = (bid >> 2) & 7;
    const int n  = (bid >> 5) & 7;
    const int b  = bid >> 8;
    const int tid = threadIdx.x;
    const int wave = tid >> 6, lane = tid & 63;
    const int lr = lane & 15, quad = lane >> 4;
    const int q0 = qt * 128;
    const int i0 = q0 + 16 * wave;

    // T5 bias table (512 entries, one per thread)
    {
        int nd = tid;
        int bucket;
        if (nd < 16) bucket = nd;
        else {
            int vbk = 16 + (int)(log((double)nd * (1.0 / 16.0)) * (16.0 / log(8.0)));
            bucket = vbk < 31 ? vbk : 31;
        }
        bias_s[nd] = rel_bias[h * 32 + bucket];
    }
    const float bias31 = rel_bias[h * 32 + 31];

    // Q B-frag direct from global
    s16x8 aq[2];
    {
        const short* src = qb + (size_t)(b * S_ + n * W_ + i0 + lr) * 512 + h * 64 + quad * 8;
        aq[0] = *(const s16x8*)(src);
        aq[1] = *(const s16x8*)(src + 32);
    }

    f32x4 oacc[4] = {};
    float lsum = 0.f;

    const int cmin = (16 * wave) >> 6;
    const int cmax = (16 * wave + 527) >> 6;

    const int r8 = lane >> 3, gr = lane & 7;

    // async staging: wave w stages rows 8w..8w+7 of K chunk and of V^T chunk
    // keys for chunk c are jj in [q0 + 64c, q0 + 64c + 64)  (window coords)
    auto issueKV = [&](int c, int pb) {
        int jj = q0 + 64 * c + 8 * wave + r8;          // key in [q0, q0+640)
        int p  = n * W_ + jj - W_;
        int gs = gr ^ r8;
        const short* ksrc = (p >= 0)
            ? kb   + ((size_t)(b * S_ + p)) * 512 + h * 64 + gs * 8
            : pkbf + (((size_t)(b * W_ + jj)) * 8 + h) * 64 + gs * 8;
        gl_lds16(ksrc, &k_s[pb][8 * wave][0]);
        int drow = 8 * wave + r8;
        const short* vsrc = vbt + (size_t)(h * 64 + drow) * 9216
                          + b * 4608 + n * W_ + q0 + 64 * c + gs * 8;
        gl_lds16(vsrc, &vt_s[pb][8 * wave][0]);
    };

    issueKV(0, 0);

    for (int c = 0; c < 10; ++c) {
        const int pb = c & 1;
        drain_vmem();                    // our async writes land BEFORE barrier
        __syncthreads();                 // now all waves' chunk-c rows are valid
        if (c < 9) issueKV(c + 1, pb ^ 1);   // overlaps compute below
        if (c < cmin || c > cmax) continue;

        // ---- S^T = K * Q^T : D[key][q], col=lane&15=q, row=quad*4+rg=key ----
        f32x4 sacc[4] = {};
        #pragma unroll
        for (int ks = 0; ks < 2; ++ks) {
            s16x8 bk[4];
            #pragma unroll
            for (int tn = 0; tn < 4; ++tn)
                bk[tn] = *(const s16x8*)&k_s[pb][tn * 16 + lr][(((4 * ks + quad) ^ (lr & 7)) * 8)];
            #pragma unroll
            for (int tn = 0; tn < 4; ++tn)
                sacc[tn] = __builtin_amdgcn_mfma_f32_16x16x32_bf16(
                    bk[tn], aq[ks], sacc[tn], 0, 0, 0);
        }

        // ---- bias + mask + exp (no running max needed) ----
        const int ib = i0 + lr;          // this lane's q row (window coords)
        const int jb = q0 + 64 * c;
        if (64 * c - 16 * wave <= 336) {
            // all valid pairs have nd >= 113 -> bucket 31 (constant bias)
            #pragma unroll
            for (int tn = 0; tn < 4; ++tn) {
                s16x4 pp;
                #pragma unroll
                for (int rg = 0; rg < 4; ++rg) {
                    int j = jb + tn * 16 + quad * 4 + rg;
                    unsigned dm1 = (unsigned)(j - ib - 1);
                    float sv = (dm1 < 512u) ? (sacc[tn][rg] + bias31) : MASKV;
                    float p = __expf(sv);
                    lsum += p;
                    pp[rg] = f2bf(p);
                }
                int gp = (2 * tn + (quad >> 1)) ^ (lr & 7);
                *(s16x4*)&p_s[16 * wave + lr][gp * 8 + (quad & 1) * 4] = pp;
            }
        } else {
            #pragma unroll
            for (int tn = 0; tn < 4; ++tn) {
                s16x4 pp;
                #pragma unroll
                for (int rg = 0; rg < 4; ++rg) {
                    int j = jb + tn * 16 + quad * 4 + rg;
                    unsigned dm1 = (unsigned)(j - ib - 1);
                    float bias = bias_s[(ib + 512 - j) & 511];
                    float sv = (dm1 < 512u) ? (sacc[tn][rg] + bias) : MASKV;
                    float p = __expf(sv);
                    lsum += p;
                    pp[rg] = f2bf(p);
                }
                int gp = (2 * tn + (quad >> 1)) ^ (lr & 7);
                *(s16x4*)&p_s[16 * wave + lr][gp * 8 + (quad & 1) * 4] = pp;
            }
        }

        asm volatile("s_waitcnt lgkmcnt(0)" ::: "memory");

        // ---- O += P V : A=P (q x keys), B=V (keys x d) ----
        #pragma unroll
        for (int ks = 0; ks < 2; ++ks) {
            int gpa = (4 * ks + quad) ^ (lr & 7);
            s16x8 ap = *(const s16x8*)&p_s[16 * wave + lr][gpa * 8];
            s16x8 bv[4];
            #pragma unroll
            for (int tn = 0; tn < 4; ++tn)
                bv[tn] = *(const s16x8*)&vt_s[pb][tn * 16 + lr][(((4 * ks + quad) ^ (lr & 7)) * 8)];
            #pragma unroll
            for (int tn = 0; tn < 4; ++tn)
                oacc[tn] = __builtin_amdgcn_mfma_f32_16x16x32_bf16(
                    ap, bv[tn], oacc[tn], 0, 0, 0);
        }
    }

    // ---- final l reduction over quads; redistribute; store ----
    lsum += __shfl_xor(lsum, 16);
    lsum += __shfl_xor(lsum, 32);
    float linv[4];
    #pragma unroll
    for (int rg = 0; rg < 4; ++rg)
        linv[rg] = 1.0f / __shfl(lsum, quad * 4 + rg);

    #pragma unroll
    for (int rg = 0; rg < 4; ++rg) {
        int row = i0 + quad * 4 + rg;
        float* dst = out + (((size_t)b * S_ + n * W_ + row) * H_ + h) * D_ + lr;
        #pragma unroll
        for (int tn = 0; tn < 4; ++tn)
            dst[tn * 16] = oacc[tn][rg] * linv[rg];
    }
}

extern "C" void kernel_launch(void* const* d_in, const int* in_sizes, int n_in,
                              void* d_out, int out_size, void* d_ws, size_t ws_size,
                              hipStream_t stream)
{
    const float* xs       = (const float*)d_in[0];
    const float* prev_k   = (const float*)d_in[1];
    const float* prev_v   = (const float*)d_in[2];
    const float* w_q      = (const float*)d_in[3];
    const float* w_k      = (const float*)d_in[4];
    const float* w_v      = (const float*)d_in[5];
    const float* rel_bias = (const float*)d_in[6];
    float* out = (float*)d_out;

    short* xsbf = (short*)d_ws;                         // 4,194,304
    short* wt   = xsbf + (size_t)4194304;               //   786,432
    short* qkbf = wt   + (size_t)786432;                // 8,388,608 (q then k)
    short* pkbf = qkbf + (size_t)8388608;               //   524,288
    short* vbt  = pkbf + (size_t)524288;                // 512 x 9216

    prep_kernel<<<2624, 256, 0, stream>>>(xs, prev_k, prev_v, w_q, w_k, w_v,
                                          xsbf, pkbf, vbt, wt);

    proj_kernel<<<dim3(64, 12), 256, 0, stream>>>(xsbf, wt, qkbf, vbt, out);

    attn_kernel<<<512, 512, 0, stream>>>(qkbf, vbt, pkbf, rel_bias, out);
}